// Round 1
// baseline (621.122 us; speedup 1.0000x reference)
//
#include <hip/hip_runtime.h>

#define NN 100000
#define CC 128
#define HHEADS 8
#define EE 1600000

typedef unsigned short u16;
typedef unsigned int u32;
typedef __attribute__((ext_vector_type(8))) u16 u16x8;
typedef __attribute__((ext_vector_type(4))) u16 u16x4;
typedef __attribute__((ext_vector_type(8))) __bf16 bf16x8;
typedef __attribute__((ext_vector_type(4))) float f32x4;

__device__ __forceinline__ float bf2f(u16 u) {
    union { u32 i; float f; } v; v.i = ((u32)u) << 16; return v.f;
}
__device__ __forceinline__ u16 f2bf(float f) {
    union { float f; u32 i; } v; v.f = f;
    u32 r = v.i + 0x7FFFu + ((v.i >> 16) & 1u);
    return (u16)(r >> 16);
}

__device__ __forceinline__ f32x4 mfma16(u16x8 a, u16x8 b, f32x4 c) {
    return __builtin_amdgcn_mfma_f32_16x16x32_bf16(
        __builtin_bit_cast(bf16x8, a), __builtin_bit_cast(bf16x8, b), c, 0, 0, 0);
}

// ---------------- f32 -> bf16 conversion (vectorized) ----------------
__global__ __launch_bounds__(256) void k_cvt(const float* __restrict__ in,
                                             u16* __restrict__ out, int n) {
    int stride = gridDim.x * blockDim.x * 4;
    for (int i = (blockIdx.x * blockDim.x + threadIdx.x) * 4; i < n; i += stride) {
        float4 v = *(const float4*)(in + i);
        u16x4 o;
        o.x = f2bf(v.x); o.y = f2bf(v.y); o.z = f2bf(v.z); o.w = f2bf(v.w);
        *(u16x4*)(out + i) = o;
    }
}

// ---------------- bf16 MFMA GEMM: out = A[M,K] @ B[NC,K]^T (+bias,+resid,relu) ----
// 128x128 tile, BK=64, 4 waves (2x2), each wave 64x64 via 4x4 16x16x32 MFMA frags.
template<int K, bool BIAS, bool RELU, bool RESID>
__global__ __launch_bounds__(256, 2) void k_gemm(
    const u16* __restrict__ A, const u16* __restrict__ B,
    const float* __restrict__ bias, const float* __restrict__ resid,
    float* __restrict__ outf, u16* __restrict__ outb, int M, int NC)
{
    __shared__ u16 As[128 * 64];
    __shared__ u16 Bs[128 * 64];
    const int tid = threadIdx.x;
    const int lane = tid & 63;
    const int w = tid >> 6;
    const int wr = w >> 1, wc = w & 1;
    const int row0 = blockIdx.x * 128;
    const int col0 = blockIdx.y * 128;
    f32x4 acc[4][4] = {};

    for (int kt = 0; kt < K; kt += 64) {
#pragma unroll
        for (int i = 0; i < 4; i++) {
            int c = i * 256 + tid;        // chunk id: lane-contiguous within wave
            int r = c >> 3;               // tile row 0..127
            int kc = (c & 7) * 8;         // k element offset within BK
            int ar = row0 + r; ar = ar < M ? ar : M - 1;
            __builtin_amdgcn_global_load_lds(
                (const __attribute__((address_space(1))) u32*)(A + (size_t)ar * K + kt + kc),
                (__attribute__((address_space(3))) u32*)(As + c * 8), 16, 0, 0);
            __builtin_amdgcn_global_load_lds(
                (const __attribute__((address_space(1))) u32*)(B + (size_t)(col0 + r) * K + kt + kc),
                (__attribute__((address_space(3))) u32*)(Bs + c * 8), 16, 0, 0);
        }
        asm volatile("s_waitcnt vmcnt(0)" ::: "memory");
        __syncthreads();
#pragma unroll
        for (int kk = 0; kk < 2; kk++) {
            const int ko = kk * 32 + (lane >> 4) * 8;
            u16x8 af[4], bfr[4];
#pragma unroll
            for (int m = 0; m < 4; m++)
                af[m] = *(const u16x8*)(As + (wr * 64 + m * 16 + (lane & 15)) * 64 + ko);
#pragma unroll
            for (int n = 0; n < 4; n++)
                bfr[n] = *(const u16x8*)(Bs + (wc * 64 + n * 16 + (lane & 15)) * 64 + ko);
#pragma unroll
            for (int m = 0; m < 4; m++)
#pragma unroll
                for (int n = 0; n < 4; n++)
                    acc[m][n] = mfma16(af[m], bfr[n], acc[m][n]);
        }
        __syncthreads();
    }

    // epilogue: C/D layout col=lane&15, row=(lane>>4)*4+j  [m89-verified]
    const int rbase = wr * 64 + ((lane >> 4) << 2);
    const int cbase = col0 + wc * 64 + (lane & 15);
#pragma unroll
    for (int m = 0; m < 4; m++) {
#pragma unroll
        for (int j = 0; j < 4; j++) {
            int gr = row0 + rbase + m * 16 + j;
            if (gr < M) {
                size_t rowoff = (size_t)gr * NC;
#pragma unroll
                for (int n = 0; n < 4; n++) {
                    int gc = cbase + n * 16;
                    float v = acc[m][n][j];
                    if constexpr (BIAS)  v += bias[gc];
                    if constexpr (RESID) v += resid[rowoff + gc];
                    if constexpr (RELU)  v = fmaxf(v, 0.f);
                    if (outf) outf[rowoff + gc] = v;
                    if (outb) outb[rowoff + gc] = f2bf(v);
                }
            }
        }
    }
}

// ---------------- CSR build ----------------
__global__ __launch_bounds__(256) void k_hist(const int* __restrict__ dst,
                                              int* __restrict__ counts, int n) {
    for (int i = blockIdx.x * blockDim.x + threadIdx.x; i < n; i += gridDim.x * blockDim.x)
        atomicAdd(&counts[dst[i]], 1);
}

__global__ __launch_bounds__(256) void k_scan1(const int* __restrict__ in,
                                               int* __restrict__ outE,
                                               int* __restrict__ part, int n) {
    __shared__ int sa[256], sb[256];
    int t = threadIdx.x, idx = blockIdx.x * 256 + t;
    int v = (idx < n) ? in[idx] : 0;
    int* s = sa; int* d = sb;
    s[t] = v; __syncthreads();
    for (int o = 1; o < 256; o <<= 1) {
        int val = s[t] + ((t >= o) ? s[t - o] : 0);
        d[t] = val; __syncthreads();
        int* tmp = s; s = d; d = tmp;
    }
    if (idx < n) outE[idx] = s[t] - v;
    if (t == 255) part[blockIdx.x] = s[t];
}

__global__ __launch_bounds__(512) void k_scan2(int* __restrict__ part, int nb) {
    __shared__ int sa[512], sb[512];
    int t = threadIdx.x;
    int v = (t < nb) ? part[t] : 0;
    int* s = sa; int* d = sb;
    s[t] = v; __syncthreads();
    for (int o = 1; o < 512; o <<= 1) {
        int val = s[t] + ((t >= o) ? s[t - o] : 0);
        d[t] = val; __syncthreads();
        int* tmp = s; s = d; d = tmp;
    }
    if (t < nb) part[t] = s[t] - v;
}

__global__ __launch_bounds__(256) void k_scan3(int* __restrict__ offs,
                                               const int* __restrict__ part,
                                               int n, int total) {
    int idx = blockIdx.x * 256 + threadIdx.x;
    if (idx < n) offs[idx] += part[idx >> 8];
    if (idx == 0) offs[n] = total;
}

__global__ __launch_bounds__(256) void k_scatter(const int* __restrict__ src,
                                                 const int* __restrict__ dst,
                                                 const int* __restrict__ offs,
                                                 int* __restrict__ cursor,
                                                 int* __restrict__ csr, int n) {
    for (int i = blockIdx.x * blockDim.x + threadIdx.x; i < n; i += gridDim.x * blockDim.x) {
        int d = dst[i];
        int pos = atomicAdd(&cursor[d], 1);
        csr[offs[d] + pos] = src[i];
    }
}

// ---------------- GAT aggregation: one block (128 thr = 8 heads x 16) per node ----
__global__ __launch_bounds__(128) void k_gat(const u16* __restrict__ xlr,
                                             const int* __restrict__ csr,
                                             const int* __restrict__ offs,
                                             const float* __restrict__ att,
                                             const float* __restrict__ gbias,
                                             u16* __restrict__ x1b)
{
    int node = blockIdx.x;
    int t = threadIdx.x;                      // t = h*16 + d
    float a_hd = att[t];
    float xr_v = bf2f(xlr[(size_t)node * 256 + 128 + t]);
    int beg = offs[node], end = offs[node + 1];
    float m = -3.4e38f, s = 0.f, acc = 0.f;
    int sn = (beg < end) ? csr[beg] : 0;
    float xl_n = (beg < end) ? bf2f(xlr[(size_t)sn * 256 + t]) : 0.f;
    for (int e = beg; e < end; e++) {
        float xl = xl_n;
        if (e + 1 < end) {
            int s2 = csr[e + 1];
            xl_n = bf2f(xlr[(size_t)s2 * 256 + t]);   // prefetch next row
        }
        float tv = xl + xr_v;
        tv = (tv > 0.f) ? tv : 0.2f * tv;             // leaky_relu(0.2)
        float p = tv * a_hd;                          // dot with att over d (16 lanes)
        p += __shfl_xor(p, 1, 16);
        p += __shfl_xor(p, 2, 16);
        p += __shfl_xor(p, 4, 16);
        p += __shfl_xor(p, 8, 16);
        if (p > m) {                                  // online softmax
            float sc = __expf(m - p);
            s = s * sc + 1.f;
            acc = acc * sc + xl;
            m = p;
        } else {
            float wgt = __expf(p - m);
            s += wgt;
            acc += wgt * xl;
        }
    }
    float o = acc / (s + 1e-16f) + gbias[t];
    x1b[(size_t)node * CC + t] = f2bf(o);
}

// ---------------- LayerNorm: one wave per row ----------------
__global__ __launch_bounds__(256) void k_ln(const float* __restrict__ x,
                                            const float* __restrict__ g,
                                            const float* __restrict__ b,
                                            float* __restrict__ outf,
                                            u16* __restrict__ outb, int n)
{
    int row = blockIdx.x * 4 + (threadIdx.x >> 6);
    if (row >= n) return;
    int lane = threadIdx.x & 63;
    const float* xr = x + (size_t)row * CC;
    float v0 = xr[lane], v1 = xr[lane + 64];
    float s = v0 + v1;
    for (int o = 32; o; o >>= 1) s += __shfl_xor(s, o);
    float mu = s * (1.f / 128.f);
    float d0 = v0 - mu, d1 = v1 - mu;
    float q = d0 * d0 + d1 * d1;
    for (int o = 32; o; o >>= 1) q += __shfl_xor(q, o);
    float rs = rsqrtf(q * (1.f / 128.f) + 1e-5f);
    float y0 = fmaf(d0 * rs, g[lane], b[lane]);
    float y1 = fmaf(d1 * rs, g[lane + 64], b[lane + 64]);
    size_t o0 = (size_t)row * CC + lane;
    if (outf) { outf[o0] = y0; outf[o0 + 64] = y1; }
    if (outb) { outb[o0] = f2bf(y0); outb[o0 + 64] = f2bf(y1); }
}

extern "C" void kernel_launch(void* const* d_in, const int* in_sizes, int n_in,
                              void* d_out, int out_size, void* d_ws, size_t ws_size,
                              hipStream_t stream) {
    const float* x0    = (const float*)d_in[0];
    const int*   edges = (const int*)d_in[1];      // [2,E]: src row, dst row
    const float* lin_l = (const float*)d_in[2];
    const float* lin_r = (const float*)d_in[3];
    const float* att   = (const float*)d_in[4];
    const float* gbias = (const float*)d_in[5];
    const float* Ww    = (const float*)d_in[6];
    const float* g1    = (const float*)d_in[7];
    const float* b1    = (const float*)d_in[8];
    const float* w1    = (const float*)d_in[9];
    const float* mb1   = (const float*)d_in[10];
    const float* w2    = (const float*)d_in[11];
    const float* mb2   = (const float*)d_in[12];
    const float* g2    = (const float*)d_in[13];
    const float* b2    = (const float*)d_in[14];
    float* out = (float*)d_out;

    char* ws = (char*)d_ws;
    size_t off = 0;
    auto alloc = [&](size_t bytes) {
        char* p = ws + off;
        off += (bytes + 255) & ~(size_t)255;
        return p;
    };
    u16*   x0b   = (u16*)alloc((size_t)NN * CC * 2);      // later reused as x3b
    u16*   xlr   = (u16*)alloc((size_t)NN * 256 * 2);     // later reused as hb
    u16*   x1b   = (u16*)alloc((size_t)NN * CC * 2);
    float* x2f   = (float*)alloc((size_t)NN * CC * 4);    // later reused as x4f
    float* x3f   = (float*)alloc((size_t)NN * CC * 4);
    u16*   Wa    = (u16*)alloc(256 * 128 * 2);            // [lin_l ; lin_r]
    u16*   Wb    = (u16*)alloc(128 * 128 * 2);
    u16*   W1    = (u16*)alloc(256 * 128 * 2);
    u16*   W2    = (u16*)alloc(128 * 256 * 2);
    int*   counts   = (int*)alloc((size_t)NN * 4);
    int*   cursor   = (int*)alloc((size_t)NN * 4);
    int*   offs     = (int*)alloc((size_t)(NN + 1) * 4);
    int*   partials = (int*)alloc(2048);
    int*   csr      = (int*)alloc((size_t)EE * 4);
    u16*   x3b = x0b;     // x0b dead after stage-1 GEMM
    u16*   hb  = xlr;     // xlr dead after k_gat
    float* x4f = x2f;     // x2f dead after LN1
    (void)in_sizes; (void)n_in; (void)out_size; (void)ws_size;

    // 1) bf16 conversions
    k_cvt<<<2048, 256, 0, stream>>>(x0, x0b, NN * CC);
    k_cvt<<<16, 256, 0, stream>>>(lin_l, Wa, 16384);
    k_cvt<<<16, 256, 0, stream>>>(lin_r, Wa + 16384, 16384);
    k_cvt<<<16, 256, 0, stream>>>(Ww, Wb, 16384);
    k_cvt<<<32, 256, 0, stream>>>(w1, W1, 32768);
    k_cvt<<<32, 256, 0, stream>>>(w2, W2, 32768);

    // 2) stage-1 GEMM: [x_l | x_r] = x0 @ [lin_l;lin_r]^T  -> xlr bf16 [N,256]
    k_gemm<128, false, false, false><<<dim3(782, 2), 256, 0, stream>>>(
        x0b, Wa, nullptr, nullptr, nullptr, xlr, NN, 256);

    // 3) CSR build (by dst)
    hipMemsetAsync(counts, 0, (size_t)NN * 4, stream);
    hipMemsetAsync(cursor, 0, (size_t)NN * 4, stream);
    k_hist<<<1024, 256, 0, stream>>>(edges + EE, counts, EE);
    k_scan1<<<391, 256, 0, stream>>>(counts, offs, partials, NN);
    k_scan2<<<1, 512, 0, stream>>>(partials, 391);
    k_scan3<<<391, 256, 0, stream>>>(offs, partials, NN, EE);
    k_scatter<<<1024, 256, 0, stream>>>(edges, edges + EE, offs, cursor, csr, EE);

    // 4) GAT aggregation -> x1 bf16
    k_gat<<<NN, 128, 0, stream>>>(xlr, csr, offs, att, gbias, x1b);

    // 5) x2 = x1 @ W^T + x0   (f32 out)
    k_gemm<128, false, false, true><<<dim3(782, 1), 256, 0, stream>>>(
        x1b, Wb, nullptr, x0, x2f, nullptr, NN, 128);

    // 6) x3 = LN(x2)  (f32 + bf16)
    k_ln<<<25000, 256, 0, stream>>>(x2f, g1, b1, x3f, x3b, NN);

    // 7) h = relu(x3 @ mlp_w1^T + b1)  -> bf16 [N,256]
    k_gemm<128, true, true, false><<<dim3(782, 2), 256, 0, stream>>>(
        x3b, W1, mb1, nullptr, nullptr, hb, NN, 256);

    // 8) x4 = h @ mlp_w2^T + b2 + x3  (f32)
    k_gemm<256, true, false, true><<<dim3(782, 1), 256, 0, stream>>>(
        hb, W2, mb2, x3f, x4f, nullptr, NN, 128);

    // 9) out = LN(x4)
    k_ln<<<25000, 256, 0, stream>>>(x4f, g2, b2, out, nullptr, NN);
}

// Round 2
// 485.022 us; speedup vs baseline: 1.2806x; 1.2806x over previous
//
#include <hip/hip_runtime.h>

#define NN 100000
#define CC 128
#define HHEADS 8
#define EE 1600000

typedef unsigned short u16;
typedef unsigned int u32;
typedef __attribute__((ext_vector_type(8))) u16 u16x8;
typedef __attribute__((ext_vector_type(4))) u16 u16x4;
typedef __attribute__((ext_vector_type(8))) __bf16 bf16x8;
typedef __attribute__((ext_vector_type(4))) float f32x4;

__device__ __forceinline__ float bf2f(u16 u) {
    union { u32 i; float f; } v; v.i = ((u32)u) << 16; return v.f;
}
__device__ __forceinline__ u16 f2bf(float f) {
    union { float f; u32 i; } v; v.f = f;
    u32 r = v.i + 0x7FFFu + ((v.i >> 16) & 1u);
    return (u16)(r >> 16);
}

__device__ __forceinline__ f32x4 mfma16(u16x8 a, u16x8 b, f32x4 c) {
    return __builtin_amdgcn_mfma_f32_16x16x32_bf16(
        __builtin_bit_cast(bf16x8, a), __builtin_bit_cast(bf16x8, b), c, 0, 0, 0);
}

// ---------------- f32 -> bf16 conversion (vectorized) ----------------
__global__ __launch_bounds__(256) void k_cvt(const float* __restrict__ in,
                                             u16* __restrict__ out, int n) {
    int stride = gridDim.x * blockDim.x * 4;
    for (int i = (blockIdx.x * blockDim.x + threadIdx.x) * 4; i < n; i += stride) {
        float4 v = *(const float4*)(in + i);
        u16x4 o;
        o.x = f2bf(v.x); o.y = f2bf(v.y); o.z = f2bf(v.z); o.w = f2bf(v.w);
        *(u16x4*)(out + i) = o;
    }
}

// ---------------- bf16 MFMA GEMM: out = A[M,K] @ B[NC,K]^T (+bias,+resid,relu) ----
// 128x128 tile, BK=64, 4 waves (2x2), each wave 64x64 via 4x4 16x16x32 MFMA frags.
template<int K, bool BIAS, bool RELU, bool RESID>
__global__ __launch_bounds__(256, 2) void k_gemm(
    const u16* __restrict__ A, const u16* __restrict__ B,
    const float* __restrict__ bias, const float* __restrict__ resid,
    float* __restrict__ outf, u16* __restrict__ outb, int M, int NC)
{
    __shared__ u16 As[128 * 64];
    __shared__ u16 Bs[128 * 64];
    const int tid = threadIdx.x;
    const int lane = tid & 63;
    const int w = tid >> 6;
    const int wr = w >> 1, wc = w & 1;
    const int row0 = blockIdx.x * 128;
    const int col0 = blockIdx.y * 128;
    f32x4 acc[4][4] = {};

    for (int kt = 0; kt < K; kt += 64) {
#pragma unroll
        for (int i = 0; i < 4; i++) {
            int c = i * 256 + tid;        // chunk id: lane-contiguous within wave
            int r = c >> 3;               // tile row 0..127
            int kc = (c & 7) * 8;         // k element offset within BK
            int ar = row0 + r; ar = ar < M ? ar : M - 1;
            __builtin_amdgcn_global_load_lds(
                (const __attribute__((address_space(1))) u32*)(A + (size_t)ar * K + kt + kc),
                (__attribute__((address_space(3))) u32*)(As + c * 8), 16, 0, 0);
            __builtin_amdgcn_global_load_lds(
                (const __attribute__((address_space(1))) u32*)(B + (size_t)(col0 + r) * K + kt + kc),
                (__attribute__((address_space(3))) u32*)(Bs + c * 8), 16, 0, 0);
        }
        asm volatile("s_waitcnt vmcnt(0)" ::: "memory");
        __syncthreads();
#pragma unroll
        for (int kk = 0; kk < 2; kk++) {
            const int ko = kk * 32 + (lane >> 4) * 8;
            u16x8 af[4], bfr[4];
#pragma unroll
            for (int m = 0; m < 4; m++)
                af[m] = *(const u16x8*)(As + (wr * 64 + m * 16 + (lane & 15)) * 64 + ko);
#pragma unroll
            for (int n = 0; n < 4; n++)
                bfr[n] = *(const u16x8*)(Bs + (wc * 64 + n * 16 + (lane & 15)) * 64 + ko);
#pragma unroll
            for (int m = 0; m < 4; m++)
#pragma unroll
                for (int n = 0; n < 4; n++)
                    acc[m][n] = mfma16(af[m], bfr[n], acc[m][n]);
        }
        __syncthreads();
    }

    // epilogue: C/D layout col=lane&15, row=(lane>>4)*4+j  [m89-verified]
    const int rbase = wr * 64 + ((lane >> 4) << 2);
    const int cbase = col0 + wc * 64 + (lane & 15);
#pragma unroll
    for (int m = 0; m < 4; m++) {
#pragma unroll
        for (int j = 0; j < 4; j++) {
            int gr = row0 + rbase + m * 16 + j;
            if (gr < M) {
                size_t rowoff = (size_t)gr * NC;
#pragma unroll
                for (int n = 0; n < 4; n++) {
                    int gc = cbase + n * 16;
                    float v = acc[m][n][j];
                    if constexpr (BIAS)  v += bias[gc];
                    if constexpr (RESID) v += resid[rowoff + gc];
                    if constexpr (RELU)  v = fmaxf(v, 0.f);
                    if (outf) outf[rowoff + gc] = v;
                    if (outb) outb[rowoff + gc] = f2bf(v);
                }
            }
        }
    }
}

// ---------------- CSR build ----------------
__global__ __launch_bounds__(256) void k_hist(const int* __restrict__ dst,
                                              int* __restrict__ counts, int n) {
    for (int i = blockIdx.x * blockDim.x + threadIdx.x; i < n; i += gridDim.x * blockDim.x)
        atomicAdd(&counts[dst[i]], 1);
}

__global__ __launch_bounds__(256) void k_scan1(const int* __restrict__ in,
                                               int* __restrict__ outE,
                                               int* __restrict__ part, int n) {
    __shared__ int sa[256], sb[256];
    int t = threadIdx.x, idx = blockIdx.x * 256 + t;
    int v = (idx < n) ? in[idx] : 0;
    int* s = sa; int* d = sb;
    s[t] = v; __syncthreads();
    for (int o = 1; o < 256; o <<= 1) {
        int val = s[t] + ((t >= o) ? s[t - o] : 0);
        d[t] = val; __syncthreads();
        int* tmp = s; s = d; d = tmp;
    }
    if (idx < n) outE[idx] = s[t] - v;
    if (t == 255) part[blockIdx.x] = s[t];
}

__global__ __launch_bounds__(512) void k_scan2(int* __restrict__ part, int nb) {
    __shared__ int sa[512], sb[512];
    int t = threadIdx.x;
    int v = (t < nb) ? part[t] : 0;
    int* s = sa; int* d = sb;
    s[t] = v; __syncthreads();
    for (int o = 1; o < 512; o <<= 1) {
        int val = s[t] + ((t >= o) ? s[t - o] : 0);
        d[t] = val; __syncthreads();
        int* tmp = s; s = d; d = tmp;
    }
    if (t < nb) part[t] = s[t] - v;
}

__global__ __launch_bounds__(256) void k_scan3(int* __restrict__ offs,
                                               const int* __restrict__ part,
                                               int n, int total) {
    int idx = blockIdx.x * 256 + threadIdx.x;
    if (idx < n) offs[idx] += part[idx >> 8];
    if (idx == 0) offs[n] = total;
}

__global__ __launch_bounds__(256) void k_scatter(const int* __restrict__ src,
                                                 const int* __restrict__ dst,
                                                 const int* __restrict__ offs,
                                                 int* __restrict__ cursor,
                                                 int* __restrict__ csr, int n) {
    for (int i = blockIdx.x * blockDim.x + threadIdx.x; i < n; i += gridDim.x * blockDim.x) {
        int d = dst[i];
        int pos = atomicAdd(&cursor[d], 1);
        csr[offs[d] + pos] = src[i];
    }
}

// ---------------- GAT aggregation ----------------
// One WAVE per node; lane = h*8 + dp handles channels c0=h*16+dp*2, c0+1.
// 4-edge unrolled, branch-free online softmax in exp2 domain.
__global__ __launch_bounds__(256) void k_gat(const u16* __restrict__ xlr,
                                             const int* __restrict__ csr,
                                             const int* __restrict__ offs,
                                             const float* __restrict__ att,
                                             const float* __restrict__ gbias,
                                             u16* __restrict__ x1b)
{
    const int node = blockIdx.x * 4 + (threadIdx.x >> 6);   // 4 waves/block, 1 node/wave
    const int lane = threadIdx.x & 63;
    const int c0 = ((lane >> 3) << 4) + ((lane & 7) << 1);  // channel pair
    const float L2E = 1.44269504f;

    const float a0 = att[c0], a1 = att[c0 + 1];
    const u32 xrp = *(const u32*)(xlr + (size_t)node * 256 + 128 + c0);
    const float xr0 = bf2f((u16)xrp), xr1 = bf2f((u16)(xrp >> 16));
    const int beg = offs[node], end = offs[node + 1];

    float m = -3.4e38f, s = 0.f, acc0 = 0.f, acc1 = 0.f;

    u32 xg[4];
    auto loadgrp = [&](int ee) {
#pragma unroll
        for (int i = 0; i < 4; i++) {
            int t = ee + i; t = t < end - 1 ? t : end - 1;
            int idx = csr[t];
            xg[i] = *(const u32*)(xlr + (size_t)idx * 256 + c0);
        }
    };
    if (beg < end) loadgrp(beg);

    for (int e = beg; e < end; e += 4) {
        u32 cur0 = xg[0], cur1 = xg[1], cur2 = xg[2], cur3 = xg[3];
        if (e + 4 < end) loadgrp(e + 4);   // prefetch next group (hides gather latency)

        float xl0[4], xl1[4], p[4];
        u32 curs[4] = {cur0, cur1, cur2, cur3};
#pragma unroll
        for (int i = 0; i < 4; i++) {
            xl0[i] = bf2f((u16)curs[i]);
            xl1[i] = bf2f((u16)(curs[i] >> 16));
            float t0 = xl0[i] + xr0; t0 = (t0 > 0.f) ? t0 : 0.2f * t0;
            float t1 = xl1[i] + xr1; t1 = (t1 > 0.f) ? t1 : 0.2f * t1;
            float pp = fmaf(t0, a0, t1 * a1);
            pp += __shfl_xor(pp, 1, 8);
            pp += __shfl_xor(pp, 2, 8);
            pp += __shfl_xor(pp, 4, 8);
            p[i] = (e + i < end) ? pp * L2E : -INFINITY;
        }
        float mnew = fmaxf(m, fmaxf(fmaxf(p[0], p[1]), fmaxf(p[2], p[3])));
        float sc = exp2f(m - mnew);
        float w0 = exp2f(p[0] - mnew), w1 = exp2f(p[1] - mnew);
        float w2 = exp2f(p[2] - mnew), w3 = exp2f(p[3] - mnew);
        s = fmaf(s, sc, (w0 + w1) + (w2 + w3));
        acc0 = fmaf(acc0, sc, fmaf(w0, xl0[0], fmaf(w1, xl0[1], fmaf(w2, xl0[2], w3 * xl0[3]))));
        acc1 = fmaf(acc1, sc, fmaf(w0, xl1[0], fmaf(w1, xl1[1], fmaf(w2, xl1[2], w3 * xl1[3]))));
        m = mnew;
    }

    float inv = 1.f / (s + 1e-16f);
    float o0 = acc0 * inv + gbias[c0];
    float o1 = acc1 * inv + gbias[c0 + 1];
    u32 pk = (u32)f2bf(o0) | ((u32)f2bf(o1) << 16);
    *(u32*)(x1b + (size_t)node * CC + c0) = pk;
}

// ---------------- LayerNorm: one wave per row ----------------
__global__ __launch_bounds__(256) void k_ln(const float* __restrict__ x,
                                            const float* __restrict__ g,
                                            const float* __restrict__ b,
                                            float* __restrict__ outf,
                                            u16* __restrict__ outb, int n)
{
    int row = blockIdx.x * 4 + (threadIdx.x >> 6);
    if (row >= n) return;
    int lane = threadIdx.x & 63;
    const float* xr = x + (size_t)row * CC;
    float v0 = xr[lane], v1 = xr[lane + 64];
    float s = v0 + v1;
    for (int o = 32; o; o >>= 1) s += __shfl_xor(s, o);
    float mu = s * (1.f / 128.f);
    float d0 = v0 - mu, d1 = v1 - mu;
    float q = d0 * d0 + d1 * d1;
    for (int o = 32; o; o >>= 1) q += __shfl_xor(q, o);
    float rs = rsqrtf(q * (1.f / 128.f) + 1e-5f);
    float y0 = fmaf(d0 * rs, g[lane], b[lane]);
    float y1 = fmaf(d1 * rs, g[lane + 64], b[lane + 64]);
    size_t o0 = (size_t)row * CC + lane;
    if (outf) { outf[o0] = y0; outf[o0 + 64] = y1; }
    if (outb) { outb[o0] = f2bf(y0); outb[o0 + 64] = f2bf(y1); }
}

extern "C" void kernel_launch(void* const* d_in, const int* in_sizes, int n_in,
                              void* d_out, int out_size, void* d_ws, size_t ws_size,
                              hipStream_t stream) {
    const float* x0    = (const float*)d_in[0];
    const int*   edges = (const int*)d_in[1];      // [2,E]: src row, dst row
    const float* lin_l = (const float*)d_in[2];
    const float* lin_r = (const float*)d_in[3];
    const float* att   = (const float*)d_in[4];
    const float* gbias = (const float*)d_in[5];
    const float* Ww    = (const float*)d_in[6];
    const float* g1    = (const float*)d_in[7];
    const float* b1    = (const float*)d_in[8];
    const float* w1    = (const float*)d_in[9];
    const float* mb1   = (const float*)d_in[10];
    const float* w2    = (const float*)d_in[11];
    const float* mb2   = (const float*)d_in[12];
    const float* g2    = (const float*)d_in[13];
    const float* b2    = (const float*)d_in[14];
    float* out = (float*)d_out;

    char* ws = (char*)d_ws;
    size_t off = 0;
    auto alloc = [&](size_t bytes) {
        char* p = ws + off;
        off += (bytes + 255) & ~(size_t)255;
        return p;
    };
    u16*   x0b   = (u16*)alloc((size_t)NN * CC * 2);      // later reused as x3b
    u16*   xlr   = (u16*)alloc((size_t)NN * 256 * 2);     // later reused as hb
    u16*   x1b   = (u16*)alloc((size_t)NN * CC * 2);
    float* x2f   = (float*)alloc((size_t)NN * CC * 4);    // later reused as x4f
    float* x3f   = (float*)alloc((size_t)NN * CC * 4);
    u16*   Wa    = (u16*)alloc(256 * 128 * 2);            // [lin_l ; lin_r]
    u16*   Wb    = (u16*)alloc(128 * 128 * 2);
    u16*   W1    = (u16*)alloc(256 * 128 * 2);
    u16*   W2    = (u16*)alloc(128 * 256 * 2);
    int*   counts   = (int*)alloc((size_t)NN * 4);
    int*   cursor   = (int*)alloc((size_t)NN * 4);
    int*   offs     = (int*)alloc((size_t)(NN + 1) * 4);
    int*   partials = (int*)alloc(2048);
    int*   csr      = (int*)alloc((size_t)EE * 4);
    u16*   x3b = x0b;     // x0b dead after stage-1 GEMM
    u16*   hb  = xlr;     // xlr dead after k_gat
    float* x4f = x2f;     // x2f dead after LN1
    (void)in_sizes; (void)n_in; (void)out_size; (void)ws_size;

    // 1) bf16 conversions
    k_cvt<<<2048, 256, 0, stream>>>(x0, x0b, NN * CC);
    k_cvt<<<16, 256, 0, stream>>>(lin_l, Wa, 16384);
    k_cvt<<<16, 256, 0, stream>>>(lin_r, Wa + 16384, 16384);
    k_cvt<<<16, 256, 0, stream>>>(Ww, Wb, 16384);
    k_cvt<<<32, 256, 0, stream>>>(w1, W1, 32768);
    k_cvt<<<32, 256, 0, stream>>>(w2, W2, 32768);

    // 2) stage-1 GEMM: [x_l | x_r] = x0 @ [lin_l;lin_r]^T  -> xlr bf16 [N,256]
    k_gemm<128, false, false, false><<<dim3(782, 2), 256, 0, stream>>>(
        x0b, Wa, nullptr, nullptr, nullptr, xlr, NN, 256);

    // 3) CSR build (by dst)
    hipMemsetAsync(counts, 0, (size_t)NN * 4, stream);
    hipMemsetAsync(cursor, 0, (size_t)NN * 4, stream);
    k_hist<<<1024, 256, 0, stream>>>(edges + EE, counts, EE);
    k_scan1<<<391, 256, 0, stream>>>(counts, offs, partials, NN);
    k_scan2<<<1, 512, 0, stream>>>(partials, 391);
    k_scan3<<<391, 256, 0, stream>>>(offs, partials, NN, EE);
    k_scatter<<<1024, 256, 0, stream>>>(edges, edges + EE, offs, cursor, csr, EE);

    // 4) GAT aggregation -> x1 bf16   (1 wave per node, 4 nodes per block)
    k_gat<<<NN / 4, 256, 0, stream>>>(xlr, csr, offs, att, gbias, x1b);

    // 5) x2 = x1 @ W^T + x0   (f32 out)
    k_gemm<128, false, false, true><<<dim3(782, 1), 256, 0, stream>>>(
        x1b, Wb, nullptr, x0, x2f, nullptr, NN, 128);

    // 6) x3 = LN(x2)  (f32 + bf16)
    k_ln<<<25000, 256, 0, stream>>>(x2f, g1, b1, x3f, x3b, NN);

    // 7) h = relu(x3 @ mlp_w1^T + b1)  -> bf16 [N,256]
    k_gemm<128, true, true, false><<<dim3(782, 2), 256, 0, stream>>>(
        x3b, W1, mb1, nullptr, nullptr, hb, NN, 256);

    // 8) x4 = h @ mlp_w2^T + b2 + x3  (f32)
    k_gemm<256, true, false, true><<<dim3(782, 1), 256, 0, stream>>>(
        hb, W2, mb2, x3f, x4f, nullptr, NN, 128);

    // 9) out = LN(x4)
    k_ln<<<25000, 256, 0, stream>>>(x4f, g2, b2, out, nullptr, NN);
}

// Round 3
// 484.403 us; speedup vs baseline: 1.2822x; 1.0013x over previous
//
#include <hip/hip_runtime.h>

#define NN 100000
#define CC 128
#define HHEADS 8
#define EE 1600000

typedef unsigned short u16;
typedef unsigned int u32;
typedef __attribute__((ext_vector_type(8))) u16 u16x8;
typedef __attribute__((ext_vector_type(4))) u16 u16x4;
typedef __attribute__((ext_vector_type(8))) __bf16 bf16x8;
typedef __attribute__((ext_vector_type(4))) float f32x4;

__device__ __forceinline__ float bf2f(u16 u) {
    union { u32 i; float f; } v; v.i = ((u32)u) << 16; return v.f;
}
__device__ __forceinline__ u16 f2bf(float f) {
    union { float f; u32 i; } v; v.f = f;
    u32 r = v.i + 0x7FFFu + ((v.i >> 16) & 1u);
    return (u16)(r >> 16);
}

__device__ __forceinline__ f32x4 mfma16(u16x8 a, u16x8 b, f32x4 c) {
    return __builtin_amdgcn_mfma_f32_16x16x32_bf16(
        __builtin_bit_cast(bf16x8, a), __builtin_bit_cast(bf16x8, b), c, 0, 0, 0);
}

// ---------------- f32 -> bf16 conversion (vectorized) ----------------
__global__ __launch_bounds__(256) void k_cvt(const float* __restrict__ in,
                                             u16* __restrict__ out, int n) {
    int stride = gridDim.x * blockDim.x * 4;
    for (int i = (blockIdx.x * blockDim.x + threadIdx.x) * 4; i < n; i += stride) {
        float4 v = *(const float4*)(in + i);
        u16x4 o;
        o.x = f2bf(v.x); o.y = f2bf(v.y); o.z = f2bf(v.z); o.w = f2bf(v.w);
        *(u16x4*)(out + i) = o;
    }
}

// Batched weight conversion: 5 segments in one launch.
// blocks: [0,16) lin_l, [16,32) lin_r, [32,48) Ww, [48,80) w1, [80,112) w2
__global__ __launch_bounds__(256) void k_cvtw(const float* __restrict__ s0, const float* __restrict__ s1,
                                              const float* __restrict__ s2, const float* __restrict__ s3,
                                              const float* __restrict__ s4,
                                              u16* __restrict__ d0, u16* __restrict__ d1,
                                              u16* __restrict__ d2, u16* __restrict__ d3,
                                              u16* __restrict__ d4) {
    int b = blockIdx.x;
    const float* s; u16* d; int boff;
    if (b < 16)      { s = s0; d = d0; boff = b; }
    else if (b < 32) { s = s1; d = d1; boff = b - 16; }
    else if (b < 48) { s = s2; d = d2; boff = b - 32; }
    else if (b < 80) { s = s3; d = d3; boff = b - 48; }
    else             { s = s4; d = d4; boff = b - 80; }
    int i = boff * 1024 + threadIdx.x * 4;
    float4 v = *(const float4*)(s + i);
    u16x4 o;
    o.x = f2bf(v.x); o.y = f2bf(v.y); o.z = f2bf(v.z); o.w = f2bf(v.w);
    *(u16x4*)(d + i) = o;
}

// ---------------- bf16 MFMA GEMM, BK=128, optional fused LayerNorm ----------------
// out = A[M,K] @ B[NC,K]^T  (+bias) (+bf16 resid) (relu) (then rowwise LN if LNF)
// 128x128 tile, 4 waves (2x2), each wave 64x64 via 4x4 16x16x32 MFMA frags.
// LNF requires NC==128 (full row per block); LN uses smem aliased over staging.
template<int K, bool BIAS, bool RELU, bool RESIDB, bool LNF>
__global__ __launch_bounds__(256, 2) void k_gemm(
    const u16* __restrict__ A, const u16* __restrict__ B,
    const float* __restrict__ bias, const u16* __restrict__ residb,
    const float* __restrict__ g, const float* __restrict__ bln,
    float* __restrict__ outf, u16* __restrict__ outb, int M, int NC)
{
    __shared__ __align__(16) char smem[128 * 132 * 4];   // 67.6 KB: staging / LN union
    u16* As = (u16*)smem;                  // [128][128] bf16 (32 KB)
    u16* Bs = (u16*)(smem + 32768);        // [128][128] bf16 (32 KB)
    float* lnb = (float*)smem;             // [128][132] f32 (LN phase)

    const int tid = threadIdx.x;
    const int lane = tid & 63;
    const int w = tid >> 6;
    const int wr = w >> 1, wc = w & 1;
    const int row0 = blockIdx.x * 128;
    const int col0 = blockIdx.y * 128;
    f32x4 acc[4][4] = {};

    for (int kt = 0; kt < K; kt += 128) {
#pragma unroll
        for (int i = 0; i < 8; i++) {
            int c = i * 256 + tid;        // 0..2047
            int r = c >> 4;               // tile row 0..127
            int kc = (c & 15) * 8;        // k offset 0..120
            int ar = row0 + r; ar = ar < M ? ar : M - 1;
            __builtin_amdgcn_global_load_lds(
                (const __attribute__((address_space(1))) u32*)(A + (size_t)ar * K + kt + kc),
                (__attribute__((address_space(3))) u32*)(As + r * 128 + kc), 16, 0, 0);
            __builtin_amdgcn_global_load_lds(
                (const __attribute__((address_space(1))) u32*)(B + (size_t)(col0 + r) * K + kt + kc),
                (__attribute__((address_space(3))) u32*)(Bs + r * 128 + kc), 16, 0, 0);
        }
        asm volatile("s_waitcnt vmcnt(0)" ::: "memory");
        __syncthreads();
#pragma unroll
        for (int kk = 0; kk < 4; kk++) {
            const int ko = kk * 32 + (lane >> 4) * 8;
            u16x8 af[4], bfr[4];
#pragma unroll
            for (int m = 0; m < 4; m++)
                af[m] = *(const u16x8*)(As + (wr * 64 + m * 16 + (lane & 15)) * 128 + ko);
#pragma unroll
            for (int n = 0; n < 4; n++)
                bfr[n] = *(const u16x8*)(Bs + (wc * 64 + n * 16 + (lane & 15)) * 128 + ko);
#pragma unroll
            for (int m = 0; m < 4; m++)
#pragma unroll
                for (int n = 0; n < 4; n++)
                    acc[m][n] = mfma16(af[m], bfr[n], acc[m][n]);
        }
        __syncthreads();                  // smem reusable after this
    }

    // C/D layout: col=lane&15, row=(lane>>4)*4+j  [m89-verified]
    const int rbase = wr * 64 + ((lane >> 4) << 2);
    const int cbase = wc * 64 + (lane & 15);

    if constexpr (!LNF) {
#pragma unroll
        for (int m = 0; m < 4; m++) {
#pragma unroll
            for (int j = 0; j < 4; j++) {
                int gr = row0 + rbase + m * 16 + j;
                if (gr < M) {
                    size_t rowoff = (size_t)gr * NC;
#pragma unroll
                    for (int n = 0; n < 4; n++) {
                        int gc = col0 + cbase + n * 16;
                        float v = acc[m][n][j];
                        if constexpr (BIAS)  v += bias[gc];
                        if constexpr (RELU)  v = fmaxf(v, 0.f);
                        if (outf) outf[rowoff + gc] = v;
                        if (outb) outb[rowoff + gc] = f2bf(v);
                    }
                }
            }
        }
    } else {
        // ---- fused LayerNorm epilogue (NC==128, col0==0) ----
        // phase 1: acc (+bias)(+resid) -> lnb[128][132]
#pragma unroll
        for (int m = 0; m < 4; m++) {
#pragma unroll
            for (int j = 0; j < 4; j++) {
                int lr = rbase + m * 16 + j;
                int gr = row0 + lr; gr = gr < M ? gr : M - 1;
#pragma unroll
                for (int n = 0; n < 4; n++) {
                    int lc = cbase + n * 16;
                    float v = acc[m][n][j];
                    if constexpr (BIAS)   v += bias[lc];
                    if constexpr (RESIDB) v += bf2f(residb[(size_t)gr * 128 + lc]);
                    if constexpr (RELU)   v = fmaxf(v, 0.f);
                    lnb[lr * 132 + lc] = v;
                }
            }
        }
        __syncthreads();
        // phase 2: rowwise LN, 2 threads per row (64 cols each)
        const int r = tid >> 1, half = tid & 1;
        const f32x4* rp = (const f32x4*)(lnb + r * 132 + half * 64);
        f32x4 vv[16];
        float s = 0.f;
#pragma unroll
        for (int i = 0; i < 16; i++) {
            vv[i] = rp[i];
            s += (vv[i][0] + vv[i][1]) + (vv[i][2] + vv[i][3]);
        }
        s += __shfl_xor(s, 1);
        float mu = s * (1.f / 128.f);
        float q = 0.f;
#pragma unroll
        for (int i = 0; i < 16; i++) {
            float d0 = vv[i][0] - mu, d1 = vv[i][1] - mu;
            float d2 = vv[i][2] - mu, d3 = vv[i][3] - mu;
            q += (d0 * d0 + d1 * d1) + (d2 * d2 + d3 * d3);
        }
        q += __shfl_xor(q, 1);
        float rs = rsqrtf(q * (1.f / 128.f) + 1e-5f);
        int gr = row0 + r;
        if (gr < M) {
            size_t rowoff = (size_t)gr * 128 + half * 64;
            const f32x4* gp = (const f32x4*)(g + half * 64);
            const f32x4* bp = (const f32x4*)(bln + half * 64);
#pragma unroll
            for (int i = 0; i < 16; i++) {
                f32x4 gg = gp[i], bb = bp[i], y;
#pragma unroll
                for (int k = 0; k < 4; k++)
                    y[k] = fmaf((vv[i][k] - mu) * rs, gg[k], bb[k]);
                if (outf) *(f32x4*)(outf + rowoff + i * 4) = y;
                if (outb) {
                    u32 p0 = (u32)f2bf(y[0]) | ((u32)f2bf(y[1]) << 16);
                    u32 p1 = (u32)f2bf(y[2]) | ((u32)f2bf(y[3]) << 16);
                    *(u32*)(outb + rowoff + i * 4) = p0;
                    *(u32*)(outb + rowoff + i * 4 + 2) = p1;
                }
            }
        }
    }
}

// ---------------- CSR build ----------------
__global__ __launch_bounds__(256) void k_hist(const int* __restrict__ dst,
                                              int* __restrict__ counts, int n) {
    for (int i = blockIdx.x * blockDim.x + threadIdx.x; i < n; i += gridDim.x * blockDim.x)
        atomicAdd(&counts[dst[i]], 1);
}

__global__ __launch_bounds__(256) void k_scan1(const int* __restrict__ in,
                                               int* __restrict__ outE,
                                               int* __restrict__ part, int n) {
    __shared__ int sa[256], sb[256];
    int t = threadIdx.x, idx = blockIdx.x * 256 + t;
    int v = (idx < n) ? in[idx] : 0;
    int* s = sa; int* d = sb;
    s[t] = v; __syncthreads();
    for (int o = 1; o < 256; o <<= 1) {
        int val = s[t] + ((t >= o) ? s[t - o] : 0);
        d[t] = val; __syncthreads();
        int* tmp = s; s = d; d = tmp;
    }
    if (idx < n) outE[idx] = s[t] - v;
    if (t == 255) part[blockIdx.x] = s[t];
}

__global__ __launch_bounds__(512) void k_scan2(int* __restrict__ part, int nb) {
    __shared__ int sa[512], sb[512];
    int t = threadIdx.x;
    int v = (t < nb) ? part[t] : 0;
    int* s = sa; int* d = sb;
    s[t] = v; __syncthreads();
    for (int o = 1; o < 512; o <<= 1) {
        int val = s[t] + ((t >= o) ? s[t - o] : 0);
        d[t] = val; __syncthreads();
        int* tmp = s; s = d; d = tmp;
    }
    if (t < nb) part[t] = s[t] - v;
}

__global__ __launch_bounds__(256) void k_scan3(int* __restrict__ offs,
                                               const int* __restrict__ part,
                                               int n, int total) {
    int idx = blockIdx.x * 256 + threadIdx.x;
    if (idx < n) offs[idx] += part[idx >> 8];
    if (idx == 0) offs[n] = total;
}

__global__ __launch_bounds__(256) void k_scatter(const int* __restrict__ src,
                                                 const int* __restrict__ dst,
                                                 const int* __restrict__ offs,
                                                 int* __restrict__ cursor,
                                                 int* __restrict__ csr, int n) {
    for (int i = blockIdx.x * blockDim.x + threadIdx.x; i < n; i += gridDim.x * blockDim.x) {
        int d = dst[i];
        int pos = atomicAdd(&cursor[d], 1);
        csr[offs[d] + pos] = src[i];
    }
}

// ---------------- GAT aggregation ----------------
// One WAVE per node; lane = h*8 + dp handles channels c0=h*16+dp*2, c0+1.
// 4-edge unrolled, branch-free online softmax in exp2 domain.
__global__ __launch_bounds__(256) void k_gat(const u16* __restrict__ xlr,
                                             const int* __restrict__ csr,
                                             const int* __restrict__ offs,
                                             const float* __restrict__ att,
                                             const float* __restrict__ gbias,
                                             u16* __restrict__ x1b)
{
    const int node = blockIdx.x * 4 + (threadIdx.x >> 6);   // 4 waves/block, 1 node/wave
    const int lane = threadIdx.x & 63;
    const int c0 = ((lane >> 3) << 4) + ((lane & 7) << 1);  // channel pair
    const float L2E = 1.44269504f;

    const float a0 = att[c0], a1 = att[c0 + 1];
    const u32 xrp = *(const u32*)(xlr + (size_t)node * 256 + 128 + c0);
    const float xr0 = bf2f((u16)xrp), xr1 = bf2f((u16)(xrp >> 16));
    const int beg = offs[node], end = offs[node + 1];

    float m = -3.4e38f, s = 0.f, acc0 = 0.f, acc1 = 0.f;

    u32 xg[4];
    auto loadgrp = [&](int ee) {
#pragma unroll
        for (int i = 0; i < 4; i++) {
            int t = ee + i; t = t < end - 1 ? t : end - 1;
            int idx = csr[t];
            xg[i] = *(const u32*)(xlr + (size_t)idx * 256 + c0);
        }
    };
    if (beg < end) loadgrp(beg);

    for (int e = beg; e < end; e += 4) {
        u32 cur0 = xg[0], cur1 = xg[1], cur2 = xg[2], cur3 = xg[3];
        if (e + 4 < end) loadgrp(e + 4);   // prefetch next group (hides gather latency)

        float xl0[4], xl1[4], p[4];
        u32 curs[4] = {cur0, cur1, cur2, cur3};
#pragma unroll
        for (int i = 0; i < 4; i++) {
            xl0[i] = bf2f((u16)curs[i]);
            xl1[i] = bf2f((u16)(curs[i] >> 16));
            float t0 = xl0[i] + xr0; t0 = (t0 > 0.f) ? t0 : 0.2f * t0;
            float t1 = xl1[i] + xr1; t1 = (t1 > 0.f) ? t1 : 0.2f * t1;
            float pp = fmaf(t0, a0, t1 * a1);
            pp += __shfl_xor(pp, 1, 8);
            pp += __shfl_xor(pp, 2, 8);
            pp += __shfl_xor(pp, 4, 8);
            p[i] = (e + i < end) ? pp * L2E : -INFINITY;
        }
        float mnew = fmaxf(m, fmaxf(fmaxf(p[0], p[1]), fmaxf(p[2], p[3])));
        float sc = exp2f(m - mnew);
        float w0 = exp2f(p[0] - mnew), w1 = exp2f(p[1] - mnew);
        float w2 = exp2f(p[2] - mnew), w3 = exp2f(p[3] - mnew);
        s = fmaf(s, sc, (w0 + w1) + (w2 + w3));
        acc0 = fmaf(acc0, sc, fmaf(w0, xl0[0], fmaf(w1, xl0[1], fmaf(w2, xl0[2], w3 * xl0[3]))));
        acc1 = fmaf(acc1, sc, fmaf(w0, xl1[0], fmaf(w1, xl1[1], fmaf(w2, xl1[2], w3 * xl1[3]))));
        m = mnew;
    }

    float inv = 1.f / (s + 1e-16f);
    float o0 = acc0 * inv + gbias[c0];
    float o1 = acc1 * inv + gbias[c0 + 1];
    u32 pk = (u32)f2bf(o0) | ((u32)f2bf(o1) << 16);
    *(u32*)(x1b + (size_t)node * CC + c0) = pk;
}

extern "C" void kernel_launch(void* const* d_in, const int* in_sizes, int n_in,
                              void* d_out, int out_size, void* d_ws, size_t ws_size,
                              hipStream_t stream) {
    const float* x0    = (const float*)d_in[0];
    const int*   edges = (const int*)d_in[1];      // [2,E]: src row, dst row
    const float* lin_l = (const float*)d_in[2];
    const float* lin_r = (const float*)d_in[3];
    const float* att   = (const float*)d_in[4];
    const float* gbias = (const float*)d_in[5];
    const float* Ww    = (const float*)d_in[6];
    const float* g1    = (const float*)d_in[7];
    const float* b1    = (const float*)d_in[8];
    const float* w1    = (const float*)d_in[9];
    const float* mb1   = (const float*)d_in[10];
    const float* w2    = (const float*)d_in[11];
    const float* mb2   = (const float*)d_in[12];
    const float* g2    = (const float*)d_in[13];
    const float* b2    = (const float*)d_in[14];
    float* out = (float*)d_out;

    char* ws = (char*)d_ws;
    size_t off = 0;
    auto alloc = [&](size_t bytes) {
        char* p = ws + off;
        off += (bytes + 255) & ~(size_t)255;
        return p;
    };
    u16*   x0b   = (u16*)alloc((size_t)NN * CC * 2);      // reused as x3b (safe: in-block RAW only)
    u16*   xlr   = (u16*)alloc((size_t)NN * 256 * 2);     // reused as hb
    u16*   x1b   = (u16*)alloc((size_t)NN * CC * 2);
    u16*   Wa    = (u16*)alloc(256 * 128 * 2);            // [lin_l ; lin_r]
    u16*   Wb    = (u16*)alloc(128 * 128 * 2);
    u16*   W1    = (u16*)alloc(256 * 128 * 2);
    u16*   W2    = (u16*)alloc(128 * 256 * 2);
    int*   counts   = (int*)alloc((size_t)NN * 4);
    int*   cursor   = (int*)alloc((size_t)NN * 4);
    int*   offs     = (int*)alloc((size_t)(NN + 1) * 4);
    int*   partials = (int*)alloc(2048);
    int*   csr      = (int*)alloc((size_t)EE * 4);
    u16*   x3b = x0b;     // x0b dead after gemm2's resid read (same block, pre-barrier)
    u16*   hb  = xlr;     // xlr dead after k_gat
    (void)in_sizes; (void)n_in; (void)out_size; (void)ws_size;

    // 1) bf16 conversions (x0 + all weights in one batched launch)
    k_cvt<<<2048, 256, 0, stream>>>(x0, x0b, NN * CC);
    k_cvtw<<<112, 256, 0, stream>>>(lin_l, lin_r, Ww, w1, w2,
                                    Wa, Wa + 16384, Wb, W1, W2);

    // 2) stage-1 GEMM: [x_l | x_r] = x0 @ [lin_l;lin_r]^T  -> xlr bf16 [N,256]
    k_gemm<128, false, false, false, false><<<dim3(782, 2), 256, 0, stream>>>(
        x0b, Wa, nullptr, nullptr, nullptr, nullptr, nullptr, xlr, NN, 256);

    // 3) CSR build (by dst)
    hipMemsetAsync(counts, 0, (size_t)NN * 4, stream);
    hipMemsetAsync(cursor, 0, (size_t)NN * 4, stream);
    k_hist<<<1024, 256, 0, stream>>>(edges + EE, counts, EE);
    k_scan1<<<391, 256, 0, stream>>>(counts, offs, partials, NN);
    k_scan2<<<1, 512, 0, stream>>>(partials, 391);
    k_scan3<<<391, 256, 0, stream>>>(offs, partials, NN, EE);
    k_scatter<<<1024, 256, 0, stream>>>(edges, edges + EE, offs, cursor, csr, EE);

    // 4) GAT aggregation -> x1 bf16   (1 wave per node, 4 nodes per block)
    k_gat<<<NN / 4, 256, 0, stream>>>(xlr, csr, offs, att, gbias, x1b);

    // 5+6) x3 = LN(x1 @ W^T + x0)  fused -> x3b bf16 only
    k_gemm<128, false, false, true, true><<<dim3(782, 1), 256, 0, stream>>>(
        x1b, Wb, nullptr, x0b, g1, b1, nullptr, x3b, NN, 128);

    // 7) h = relu(x3 @ mlp_w1^T + b1)  -> bf16 [N,256]
    k_gemm<128, true, true, false, false><<<dim3(782, 2), 256, 0, stream>>>(
        x3b, W1, mb1, nullptr, nullptr, nullptr, nullptr, hb, NN, 256);

    // 8+9) out = LN(h @ mlp_w2^T + b2 + x3)  fused -> f32 out
    k_gemm<256, true, false, true, true><<<dim3(782, 1), 256, 0, stream>>>(
        hb, W2, mb2, x3b, g2, b2, out, nullptr, NN, 128);
}

// Round 4
// 419.900 us; speedup vs baseline: 1.4792x; 1.1536x over previous
//
#include <hip/hip_runtime.h>

#define NN 100000
#define CC 128
#define HHEADS 8
#define EE 1600000
#define ELLCAP 64

typedef unsigned short u16;
typedef unsigned int u32;
typedef __attribute__((ext_vector_type(8))) u16 u16x8;
typedef __attribute__((ext_vector_type(4))) u16 u16x4;
typedef __attribute__((ext_vector_type(8))) __bf16 bf16x8;
typedef __attribute__((ext_vector_type(4))) float f32x4;

__device__ __forceinline__ float bf2f(u16 u) {
    union { u32 i; float f; } v; v.i = ((u32)u) << 16; return v.f;
}
__device__ __forceinline__ u16 f2bf(float f) {
    union { float f; u32 i; } v; v.f = f;
    u32 r = v.i + 0x7FFFu + ((v.i >> 16) & 1u);
    return (u16)(r >> 16);
}

__device__ __forceinline__ f32x4 mfma16(u16x8 a, u16x8 b, f32x4 c) {
    return __builtin_amdgcn_mfma_f32_16x16x32_bf16(
        __builtin_bit_cast(bf16x8, a), __builtin_bit_cast(bf16x8, b), c, 0, 0, 0);
}

// ---------------- init: x0 cvt + weight cvts + zero cursor, one launch ----------------
// blocks [0,2048): x0 (grid-stride, literal 2048)
// blocks [2048,2160): 5 weight segments (16/16/16/32/32 blocks)
// blocks [2160,2551): zero cursor (391 blocks)
__global__ __launch_bounds__(256) void k_init(
    const float* __restrict__ x0, u16* __restrict__ x0b,
    const float* __restrict__ s0, const float* __restrict__ s1,
    const float* __restrict__ s2, const float* __restrict__ s3,
    const float* __restrict__ s4,
    u16* __restrict__ d0, u16* __restrict__ d1, u16* __restrict__ d2,
    u16* __restrict__ d3, u16* __restrict__ d4,
    int* __restrict__ cursor)
{
    int b = blockIdx.x, tid = threadIdx.x;
    if (b < 2048) {
        const int n = NN * CC;
        const int stride = 2048 * 256 * 4;
        for (int i = (b * 256 + tid) * 4; i < n; i += stride) {
            float4 v = *(const float4*)(x0 + i);
            u16x4 o;
            o.x = f2bf(v.x); o.y = f2bf(v.y); o.z = f2bf(v.z); o.w = f2bf(v.w);
            *(u16x4*)(x0b + i) = o;
        }
    } else if (b < 2160) {
        int wb = b - 2048;
        const float* s; u16* d; int boff;
        if (wb < 16)      { s = s0; d = d0; boff = wb; }
        else if (wb < 32) { s = s1; d = d1; boff = wb - 16; }
        else if (wb < 48) { s = s2; d = d2; boff = wb - 32; }
        else if (wb < 80) { s = s3; d = d3; boff = wb - 48; }
        else              { s = s4; d = d4; boff = wb - 80; }
        int i = boff * 1024 + tid * 4;
        float4 v = *(const float4*)(s + i);
        u16x4 o;
        o.x = f2bf(v.x); o.y = f2bf(v.y); o.z = f2bf(v.z); o.w = f2bf(v.w);
        *(u16x4*)(d + i) = o;
    } else {
        int i = (b - 2160) * 256 + tid;
        if (i < NN) cursor[i] = 0;
    }
}

// ---------------- ELL scatter: ell[d*64+pos] = src ----------------
__global__ __launch_bounds__(256) void k_scatter(const int* __restrict__ src,
                                                 const int* __restrict__ dst,
                                                 int* __restrict__ cursor,
                                                 int* __restrict__ ell, int n) {
    for (int i = blockIdx.x * blockDim.x + threadIdx.x; i < n; i += gridDim.x * blockDim.x) {
        int d = dst[i];
        int pos = atomicAdd(&cursor[d], 1);
        if (pos < ELLCAP) ell[d * ELLCAP + pos] = src[i];
    }
}

// ---------------- bf16 MFMA GEMM, BK=128, optional fused slim LayerNorm ----------------
// out = A[M,K] @ B[NC,K]^T  (+bias) (+bf16 resid) (relu) (rowwise LN if LNF; needs NC=128)
// 128x128 tile, 4 waves (2x2), 4x4 16x16x32 MFMA frags per wave.
template<int K, bool BIAS, bool RELU, bool RESIDB, bool LNF>
__global__ __launch_bounds__(256, 2) void k_gemm(
    const u16* __restrict__ A, const u16* __restrict__ B,
    const float* __restrict__ bias, const u16* __restrict__ residb,
    const float* __restrict__ g, const float* __restrict__ bln,
    float* __restrict__ outf, u16* __restrict__ outb, int M, int NC)
{
    __shared__ __align__(16) u16 As[128 * 128];   // 32 KB
    __shared__ __align__(16) u16 Bs[128 * 128];   // 32 KB
    __shared__ float lsum[2][128], lsq[2][128];   // 2 KB (LN cross-wave combine)

    const int tid = threadIdx.x;
    const int lane = tid & 63;
    const int w = tid >> 6;
    const int wr = w >> 1, wc = w & 1;
    const int row0 = blockIdx.x * 128;
    const int col0 = blockIdx.y * 128;
    f32x4 acc[4][4] = {};

    for (int kt = 0; kt < K; kt += 128) {
#pragma unroll
        for (int i = 0; i < 8; i++) {
            int c = i * 256 + tid;        // 0..2047
            int r = c >> 4;               // tile row 0..127
            int kc = (c & 15) * 8;        // k offset
            int ar = row0 + r; ar = ar < M ? ar : M - 1;
            __builtin_amdgcn_global_load_lds(
                (const __attribute__((address_space(1))) u32*)(A + (size_t)ar * K + kt + kc),
                (__attribute__((address_space(3))) u32*)(As + r * 128 + kc), 16, 0, 0);
            __builtin_amdgcn_global_load_lds(
                (const __attribute__((address_space(1))) u32*)(B + (size_t)(col0 + r) * K + kt + kc),
                (__attribute__((address_space(3))) u32*)(Bs + r * 128 + kc), 16, 0, 0);
        }
        asm volatile("s_waitcnt vmcnt(0)" ::: "memory");
        __syncthreads();
#pragma unroll
        for (int kk = 0; kk < 4; kk++) {
            const int ko = kk * 32 + (lane >> 4) * 8;
            u16x8 af[4], bfr[4];
#pragma unroll
            for (int m = 0; m < 4; m++)
                af[m] = *(const u16x8*)(As + (wr * 64 + m * 16 + (lane & 15)) * 128 + ko);
#pragma unroll
            for (int n = 0; n < 4; n++)
                bfr[n] = *(const u16x8*)(Bs + (wc * 64 + n * 16 + (lane & 15)) * 128 + ko);
#pragma unroll
            for (int m = 0; m < 4; m++)
#pragma unroll
                for (int n = 0; n < 4; n++)
                    acc[m][n] = mfma16(af[m], bfr[n], acc[m][n]);
        }
        __syncthreads();
    }

    // C/D layout: col=lane&15, row=(lane>>4)*4+j  [m89-verified]
    const int rbase = wr * 64 + ((lane >> 4) << 2);
    const int cbase = wc * 64 + (lane & 15);

    if constexpr (!LNF) {
#pragma unroll
        for (int m = 0; m < 4; m++) {
#pragma unroll
            for (int j = 0; j < 4; j++) {
                int gr = row0 + rbase + m * 16 + j;
                if (gr < M) {
                    size_t rowoff = (size_t)gr * NC;
#pragma unroll
                    for (int n = 0; n < 4; n++) {
                        int gc = col0 + cbase + n * 16;
                        float v = acc[m][n][j];
                        if constexpr (BIAS)  v += bias[gc];
                        if constexpr (RELU)  v = fmaxf(v, 0.f);
                        if (outf) outf[rowoff + gc] = v;
                        if (outb) outb[rowoff + gc] = f2bf(v);
                    }
                }
            }
        }
    } else {
        // ---- slim fused LayerNorm (NC==128, col0==0), stats in-register ----
        float gv[4], bv[4];
#pragma unroll
        for (int n = 0; n < 4; n++) { gv[n] = g[cbase + n * 16]; bv[n] = bln[cbase + n * 16]; }
#pragma unroll
        for (int m = 0; m < 4; m++) {
#pragma unroll
            for (int j = 0; j < 4; j++) {
                int lr = rbase + m * 16 + j;
                int gr = row0 + lr; gr = gr < M ? gr : M - 1;
                float s = 0.f, q = 0.f;
#pragma unroll
                for (int n = 0; n < 4; n++) {
                    float v = acc[m][n][j];
                    if constexpr (BIAS)   v += bias[cbase + n * 16];
                    if constexpr (RESIDB) v += bf2f(residb[(size_t)gr * 128 + cbase + n * 16]);
                    if constexpr (RELU)   v = fmaxf(v, 0.f);
                    acc[m][n][j] = v;
                    s += v; q += v * v;
                }
                s += __shfl_xor(s, 1, 16); q += __shfl_xor(q, 1, 16);
                s += __shfl_xor(s, 2, 16); q += __shfl_xor(q, 2, 16);
                s += __shfl_xor(s, 4, 16); q += __shfl_xor(q, 4, 16);
                s += __shfl_xor(s, 8, 16); q += __shfl_xor(q, 8, 16);
                if ((lane & 15) == 0) { lsum[wc][lr] = s; lsq[wc][lr] = q; }
            }
        }
        __syncthreads();
#pragma unroll
        for (int m = 0; m < 4; m++) {
#pragma unroll
            for (int j = 0; j < 4; j++) {
                int lr = rbase + m * 16 + j;
                int gr = row0 + lr;
                if (gr < M) {
                    float s = lsum[0][lr] + lsum[1][lr];
                    float q = lsq[0][lr] + lsq[1][lr];
                    float mu = s * (1.f / 128.f);
                    float var = q * (1.f / 128.f) - mu * mu;
                    float rs = rsqrtf(var + 1e-5f);
                    size_t rowoff = (size_t)gr * 128;
#pragma unroll
                    for (int n = 0; n < 4; n++) {
                        float y = fmaf((acc[m][n][j] - mu) * rs, gv[n], bv[n]);
                        int gc = cbase + n * 16;
                        if (outf) outf[rowoff + gc] = y;
                        if (outb) outb[rowoff + gc] = f2bf(y);
                    }
                }
            }
        }
    }
}

// ---------------- GAT aggregation (ELL) ----------------
// One WAVE per node; lane = h*8 + dp handles channels c0=h*16+dp*2, c0+1.
// 4-edge unrolled, branch-free online softmax in exp2 domain.
__global__ __launch_bounds__(256) void k_gat(const u16* __restrict__ xlr,
                                             const int* __restrict__ ell,
                                             const int* __restrict__ cnt,
                                             const float* __restrict__ att,
                                             const float* __restrict__ gbias,
                                             u16* __restrict__ x1b)
{
    const int node = blockIdx.x * 4 + (threadIdx.x >> 6);   // 4 waves/block, 1 node/wave
    const int lane = threadIdx.x & 63;
    const int c0 = ((lane >> 3) << 4) + ((lane & 7) << 1);  // channel pair
    const float L2E = 1.44269504f;

    const float a0 = att[c0], a1 = att[c0 + 1];
    const u32 xrp = *(const u32*)(xlr + (size_t)node * 256 + 128 + c0);
    const float xr0 = bf2f((u16)xrp), xr1 = bf2f((u16)(xrp >> 16));
    const int beg = node * ELLCAP;
    int c = cnt[node]; c = c < ELLCAP ? c : ELLCAP;
    const int end = beg + c;

    float m = -3.4e38f, s = 0.f, acc0 = 0.f, acc1 = 0.f;

    u32 xg[4];
    auto loadgrp = [&](int ee) {
#pragma unroll
        for (int i = 0; i < 4; i++) {
            int t = ee + i; t = t < end - 1 ? t : end - 1;
            int idx = ell[t];
            xg[i] = *(const u32*)(xlr + (size_t)idx * 256 + c0);
        }
    };
    if (beg < end) loadgrp(beg);

    for (int e = beg; e < end; e += 4) {
        u32 cur0 = xg[0], cur1 = xg[1], cur2 = xg[2], cur3 = xg[3];
        if (e + 4 < end) loadgrp(e + 4);   // prefetch next group (hides gather latency)

        float xl0[4], xl1[4], p[4];
        u32 curs[4] = {cur0, cur1, cur2, cur3};
#pragma unroll
        for (int i = 0; i < 4; i++) {
            xl0[i] = bf2f((u16)curs[i]);
            xl1[i] = bf2f((u16)(curs[i] >> 16));
            float t0 = xl0[i] + xr0; t0 = (t0 > 0.f) ? t0 : 0.2f * t0;
            float t1 = xl1[i] + xr1; t1 = (t1 > 0.f) ? t1 : 0.2f * t1;
            float pp = fmaf(t0, a0, t1 * a1);
            pp += __shfl_xor(pp, 1, 8);
            pp += __shfl_xor(pp, 2, 8);
            pp += __shfl_xor(pp, 4, 8);
            p[i] = (e + i < end) ? pp * L2E : -INFINITY;
        }
        float mnew = fmaxf(m, fmaxf(fmaxf(p[0], p[1]), fmaxf(p[2], p[3])));
        float sc = exp2f(m - mnew);
        float w0 = exp2f(p[0] - mnew), w1 = exp2f(p[1] - mnew);
        float w2 = exp2f(p[2] - mnew), w3 = exp2f(p[3] - mnew);
        s = fmaf(s, sc, (w0 + w1) + (w2 + w3));
        acc0 = fmaf(acc0, sc, fmaf(w0, xl0[0], fmaf(w1, xl0[1], fmaf(w2, xl0[2], w3 * xl0[3]))));
        acc1 = fmaf(acc1, sc, fmaf(w0, xl1[0], fmaf(w1, xl1[1], fmaf(w2, xl1[2], w3 * xl1[3]))));
        m = mnew;
    }

    float inv = 1.f / (s + 1e-16f);
    float o0 = acc0 * inv + gbias[c0];
    float o1 = acc1 * inv + gbias[c0 + 1];
    u32 pk = (u32)f2bf(o0) | ((u32)f2bf(o1) << 16);
    *(u32*)(x1b + (size_t)node * CC + c0) = pk;
}

extern "C" void kernel_launch(void* const* d_in, const int* in_sizes, int n_in,
                              void* d_out, int out_size, void* d_ws, size_t ws_size,
                              hipStream_t stream) {
    const float* x0    = (const float*)d_in[0];
    const int*   edges = (const int*)d_in[1];      // [2,E]: src row, dst row
    const float* lin_l = (const float*)d_in[2];
    const float* lin_r = (const float*)d_in[3];
    const float* att   = (const float*)d_in[4];
    const float* gbias = (const float*)d_in[5];
    const float* Ww    = (const float*)d_in[6];
    const float* g1    = (const float*)d_in[7];
    const float* b1    = (const float*)d_in[8];
    const float* w1    = (const float*)d_in[9];
    const float* mb1   = (const float*)d_in[10];
    const float* w2    = (const float*)d_in[11];
    const float* mb2   = (const float*)d_in[12];
    const float* g2    = (const float*)d_in[13];
    const float* b2    = (const float*)d_in[14];
    float* out = (float*)d_out;

    char* ws = (char*)d_ws;
    size_t off = 0;
    auto alloc = [&](size_t bytes) {
        char* p = ws + off;
        off += (bytes + 255) & ~(size_t)255;
        return p;
    };
    u16*   x0b   = (u16*)alloc((size_t)NN * CC * 2);      // reused as x3b
    u16*   xlr   = (u16*)alloc((size_t)NN * 256 * 2);     // reused as hb
    u16*   x1b   = (u16*)alloc((size_t)NN * CC * 2);
    u16*   Wa    = (u16*)alloc(256 * 128 * 2);            // [lin_l ; lin_r]
    u16*   Wb    = (u16*)alloc(128 * 128 * 2);
    u16*   W1    = (u16*)alloc(256 * 128 * 2);
    u16*   W2    = (u16*)alloc(128 * 256 * 2);
    int*   cursor   = (int*)alloc((size_t)NN * 4);
    int*   ell      = (int*)alloc((size_t)NN * ELLCAP * 4);
    u16*   x3b = x0b;     // x0b dead after gemm2's resid read (same block, pre-store)
    u16*   hb  = xlr;     // xlr dead after k_gat
    (void)in_sizes; (void)n_in; (void)out_size; (void)ws_size;

    // 1) init: all conversions + zero cursor (one launch)
    k_init<<<2551, 256, 0, stream>>>(x0, x0b, lin_l, lin_r, Ww, w1, w2,
                                     Wa, Wa + 16384, Wb, W1, W2, cursor);

    // 2) stage-1 GEMM: [x_l | x_r] = x0 @ [lin_l;lin_r]^T  -> xlr bf16 [N,256]
    k_gemm<128, false, false, false, false><<<dim3(782, 2), 256, 0, stream>>>(
        x0b, Wa, nullptr, nullptr, nullptr, nullptr, nullptr, xlr, NN, 256);

    // 3) ELL scatter (by dst)
    k_scatter<<<1024, 256, 0, stream>>>(edges, edges + EE, cursor, ell, EE);

    // 4) GAT aggregation -> x1 bf16   (1 wave per node, 4 nodes per block)
    k_gat<<<NN / 4, 256, 0, stream>>>(xlr, ell, cursor, att, gbias, x1b);

    // 5+6) x3 = LN(x1 @ W^T + x0)  fused -> x3b bf16
    k_gemm<128, false, false, true, true><<<dim3(782, 1), 256, 0, stream>>>(
        x1b, Wb, nullptr, x0b, g1, b1, nullptr, x3b, NN, 128);

    // 7) h = relu(x3 @ mlp_w1^T + b1)  -> bf16 [N,256]
    k_gemm<128, true, true, false, false><<<dim3(782, 2), 256, 0, stream>>>(
        x3b, W1, mb1, nullptr, nullptr, nullptr, nullptr, hb, NN, 256);

    // 8+9) out = LN(h @ mlp_w2^T + b2 + x3)  fused -> f32 out
    k_gemm<256, true, false, true, true><<<dim3(782, 1), 256, 0, stream>>>(
        hb, W2, mb2, x3b, g2, b2, out, nullptr, NN, 128);
}

// Round 5
// 340.409 us; speedup vs baseline: 1.8246x; 1.2335x over previous
//
#include <hip/hip_runtime.h>

#define NN 100000
#define CC 128
#define HHEADS 8
#define EE 1600000
#define NB 196          // buckets of 512 nodes
#define BCAP 10240      // bucket capacity (mean 8192, +22 sigma)
#define BSTRIDE 16      // bucketCnt padded to one per 64B line

typedef unsigned short u16;
typedef unsigned int u32;
typedef __attribute__((ext_vector_type(8))) u16 u16x8;
typedef __attribute__((ext_vector_type(4))) u16 u16x4;
typedef __attribute__((ext_vector_type(8))) __bf16 bf16x8;
typedef __attribute__((ext_vector_type(4))) float f32x4;

__device__ __forceinline__ float bf2f(u16 u) {
    union { u32 i; float f; } v; v.i = ((u32)u) << 16; return v.f;
}
__device__ __forceinline__ u16 f2bf(float f) {
    union { float f; u32 i; } v; v.f = f;
    u32 r = v.i + 0x7FFFu + ((v.i >> 16) & 1u);
    return (u16)(r >> 16);
}

__device__ __forceinline__ f32x4 mfma16(u16x8 a, u16x8 b, f32x4 c) {
    return __builtin_amdgcn_mfma_f32_16x16x32_bf16(
        __builtin_bit_cast(bf16x8, a), __builtin_bit_cast(bf16x8, b), c, 0, 0, 0);
}

// ---------------- init: x0 cvt + weight cvts + zero bucket counters ----------------
// blocks [0,2048): x0; [2048,2160): 5 weight segments; 2160: zero bucketCnt
__global__ __launch_bounds__(256) void k_init(
    const float* __restrict__ x0, u16* __restrict__ x0b,
    const float* __restrict__ s0, const float* __restrict__ s1,
    const float* __restrict__ s2, const float* __restrict__ s3,
    const float* __restrict__ s4,
    u16* __restrict__ d0, u16* __restrict__ d1, u16* __restrict__ d2,
    u16* __restrict__ d3, u16* __restrict__ d4,
    int* __restrict__ bucketCnt)
{
    int b = blockIdx.x, tid = threadIdx.x;
    if (b < 2048) {
        const int n = NN * CC;
        const int stride = 2048 * 256 * 4;
        for (int i = (b * 256 + tid) * 4; i < n; i += stride) {
            float4 v = *(const float4*)(x0 + i);
            u16x4 o;
            o.x = f2bf(v.x); o.y = f2bf(v.y); o.z = f2bf(v.z); o.w = f2bf(v.w);
            *(u16x4*)(x0b + i) = o;
        }
    } else if (b < 2160) {
        int wb = b - 2048;
        const float* s; u16* d; int boff;
        if (wb < 16)      { s = s0; d = d0; boff = wb; }
        else if (wb < 32) { s = s1; d = d1; boff = wb - 16; }
        else if (wb < 48) { s = s2; d = d2; boff = wb - 32; }
        else if (wb < 80) { s = s3; d = d3; boff = wb - 48; }
        else              { s = s4; d = d4; boff = wb - 80; }
        int i = boff * 1024 + tid * 4;
        float4 v = *(const float4*)(s + i);
        u16x4 o;
        o.x = f2bf(v.x); o.y = f2bf(v.y); o.z = f2bf(v.z); o.w = f2bf(v.w);
        *(u16x4*)(d + i) = o;
    } else {
        for (int i = tid; i < NB * BSTRIDE; i += 256) bucketCnt[i] = 0;
    }
}

// ---------------- pass 1: bucket edges by dst>>9 (privatized hist + bulk reserve) ----
__global__ __launch_bounds__(256) void k_p1(const int* __restrict__ src,
                                            const int* __restrict__ dst,
                                            int* __restrict__ bucketCnt,
                                            u32* __restrict__ bucketEdges)
{
    __shared__ u32 hist[NB], base[NB], hist2[NB];
    const int b = blockIdx.x, tid = threadIdx.x;
    const int beg = b * 1563;
    const int end = (beg + 1563 < EE) ? beg + 1563 : EE;
    for (int t = tid; t < NB; t += 256) { hist[t] = 0; hist2[t] = 0; }
    __syncthreads();

    int es[7], ds[7];
#pragma unroll
    for (int j = 0; j < 7; j++) {
        int i = beg + tid + j * 256;
        if (i < end) { es[j] = src[i]; ds[j] = dst[i]; }
        else { es[j] = -1; ds[j] = 0; }
    }
#pragma unroll
    for (int j = 0; j < 7; j++)
        if (es[j] >= 0) atomicAdd(&hist[(u32)ds[j] >> 9], 1u);
    __syncthreads();
    for (int t = tid; t < NB; t += 256)
        base[t] = (u32)atomicAdd(&bucketCnt[t * BSTRIDE], (int)hist[t]);
    __syncthreads();
#pragma unroll
    for (int j = 0; j < 7; j++) {
        if (es[j] >= 0) {
            u32 bb = (u32)ds[j] >> 9;
            u32 r = atomicAdd(&hist2[bb], 1u);
            u32 pos = base[bb] + r;
            if (pos < BCAP)
                bucketEdges[(size_t)bb * BCAP + pos] = (u32)es[j] | ((u32)(ds[j] & 511) << 17);
        }
    }
}

// ---------------- pass 2: per-bucket CSR build (all in LDS, no global atomics) ------
__global__ __launch_bounds__(256) void k_p2(const int* __restrict__ bucketCnt,
                                            u32* __restrict__ bucketEdges,
                                            int* __restrict__ offs,
                                            int* __restrict__ cnt)
{
    __shared__ u32 ebuf[BCAP];                 // 40 KB
    __shared__ u32 ncnt[512], loff[512], ssum[256];
    const int b = blockIdx.x, tid = threadIdx.x;
    int n = bucketCnt[b * BSTRIDE]; n = n < BCAP ? n : BCAP;
    u32* be = bucketEdges + (size_t)b * BCAP;

    for (int i = tid; i < n; i += 256) ebuf[i] = be[i];
    ncnt[tid] = 0; ncnt[tid + 256] = 0;
    __syncthreads();
    for (int i = tid; i < n; i += 256) atomicAdd(&ncnt[(ebuf[i] >> 17) & 511], 1u);
    __syncthreads();

    u32 a0 = ncnt[2 * tid], a1 = ncnt[2 * tid + 1];
    ssum[tid] = a0 + a1;
    __syncthreads();
    for (int o = 1; o < 256; o <<= 1) {
        u32 v = ssum[tid];
        u32 add = (tid >= o) ? ssum[tid - o] : 0;
        __syncthreads();
        ssum[tid] = v + add;
        __syncthreads();
    }
    u32 excl = ssum[tid] - (a0 + a1);
    loff[2 * tid] = excl;
    loff[2 * tid + 1] = excl + a0;

    int node0 = b * 512 + 2 * tid;
    if (node0 < NN)     { offs[node0]     = b * BCAP + (int)excl;            cnt[node0]     = (int)a0; }
    if (node0 + 1 < NN) { offs[node0 + 1] = b * BCAP + (int)(excl + a0);     cnt[node0 + 1] = (int)a1; }

    ncnt[tid] = 0; ncnt[tid + 256] = 0;
    __syncthreads();
    for (int i = tid; i < n; i += 256) {
        u32 e = ebuf[i];
        u32 ln = (e >> 17) & 511;
        u32 r = atomicAdd(&ncnt[ln], 1u);
        be[loff[ln] + r] = e & 0x1FFFFu;     // in-place dense CSR (src only)
    }
}

// ---------------- bf16 MFMA GEMM, BK=128, optional fused slim LayerNorm ----------------
template<int K, bool BIAS, bool RELU, bool RESIDB, bool LNF>
__global__ __launch_bounds__(256, 2) void k_gemm(
    const u16* __restrict__ A, const u16* __restrict__ B,
    const float* __restrict__ bias, const u16* __restrict__ residb,
    const float* __restrict__ g, const float* __restrict__ bln,
    float* __restrict__ outf, u16* __restrict__ outb, int M, int NC)
{
    __shared__ __align__(16) u16 As[128 * 128];   // 32 KB
    __shared__ __align__(16) u16 Bs[128 * 128];   // 32 KB
    __shared__ float lsum[2][128], lsq[2][128];   // 2 KB

    const int tid = threadIdx.x;
    const int lane = tid & 63;
    const int w = tid >> 6;
    const int wr = w >> 1, wc = w & 1;
    const int row0 = blockIdx.x * 128;
    const int col0 = blockIdx.y * 128;
    f32x4 acc[4][4] = {};

    for (int kt = 0; kt < K; kt += 128) {
#pragma unroll
        for (int i = 0; i < 8; i++) {
            int c = i * 256 + tid;
            int r = c >> 4;
            int kc = (c & 15) * 8;
            int ar = row0 + r; ar = ar < M ? ar : M - 1;
            __builtin_amdgcn_global_load_lds(
                (const __attribute__((address_space(1))) u32*)(A + (size_t)ar * K + kt + kc),
                (__attribute__((address_space(3))) u32*)(As + r * 128 + kc), 16, 0, 0);
            __builtin_amdgcn_global_load_lds(
                (const __attribute__((address_space(1))) u32*)(B + (size_t)(col0 + r) * K + kt + kc),
                (__attribute__((address_space(3))) u32*)(Bs + r * 128 + kc), 16, 0, 0);
        }
        asm volatile("s_waitcnt vmcnt(0)" ::: "memory");
        __syncthreads();
#pragma unroll
        for (int kk = 0; kk < 4; kk++) {
            const int ko = kk * 32 + (lane >> 4) * 8;
            u16x8 af[4], bfr[4];
#pragma unroll
            for (int m = 0; m < 4; m++)
                af[m] = *(const u16x8*)(As + (wr * 64 + m * 16 + (lane & 15)) * 128 + ko);
#pragma unroll
            for (int n = 0; n < 4; n++)
                bfr[n] = *(const u16x8*)(Bs + (wc * 64 + n * 16 + (lane & 15)) * 128 + ko);
#pragma unroll
            for (int m = 0; m < 4; m++)
#pragma unroll
                for (int n = 0; n < 4; n++)
                    acc[m][n] = mfma16(af[m], bfr[n], acc[m][n]);
        }
        __syncthreads();
    }

    const int rbase = wr * 64 + ((lane >> 4) << 2);
    const int cbase = wc * 64 + (lane & 15);

    if constexpr (!LNF) {
#pragma unroll
        for (int m = 0; m < 4; m++) {
#pragma unroll
            for (int j = 0; j < 4; j++) {
                int gr = row0 + rbase + m * 16 + j;
                if (gr < M) {
                    size_t rowoff = (size_t)gr * NC;
#pragma unroll
                    for (int n = 0; n < 4; n++) {
                        int gc = col0 + cbase + n * 16;
                        float v = acc[m][n][j];
                        if constexpr (BIAS)  v += bias[gc];
                        if constexpr (RELU)  v = fmaxf(v, 0.f);
                        if (outf) outf[rowoff + gc] = v;
                        if (outb) outb[rowoff + gc] = f2bf(v);
                    }
                }
            }
        }
    } else {
        float gv[4], bv[4];
#pragma unroll
        for (int n = 0; n < 4; n++) { gv[n] = g[cbase + n * 16]; bv[n] = bln[cbase + n * 16]; }
#pragma unroll
        for (int m = 0; m < 4; m++) {
#pragma unroll
            for (int j = 0; j < 4; j++) {
                int lr = rbase + m * 16 + j;
                int gr = row0 + lr; gr = gr < M ? gr : M - 1;
                float s = 0.f, q = 0.f;
#pragma unroll
                for (int n = 0; n < 4; n++) {
                    float v = acc[m][n][j];
                    if constexpr (BIAS)   v += bias[cbase + n * 16];
                    if constexpr (RESIDB) v += bf2f(residb[(size_t)gr * 128 + cbase + n * 16]);
                    if constexpr (RELU)   v = fmaxf(v, 0.f);
                    acc[m][n][j] = v;
                    s += v; q += v * v;
                }
                s += __shfl_xor(s, 1, 16); q += __shfl_xor(q, 1, 16);
                s += __shfl_xor(s, 2, 16); q += __shfl_xor(q, 2, 16);
                s += __shfl_xor(s, 4, 16); q += __shfl_xor(q, 4, 16);
                s += __shfl_xor(s, 8, 16); q += __shfl_xor(q, 8, 16);
                if ((lane & 15) == 0) { lsum[wc][lr] = s; lsq[wc][lr] = q; }
            }
        }
        __syncthreads();
#pragma unroll
        for (int m = 0; m < 4; m++) {
#pragma unroll
            for (int j = 0; j < 4; j++) {
                int lr = rbase + m * 16 + j;
                int gr = row0 + lr;
                if (gr < M) {
                    float s = lsum[0][lr] + lsum[1][lr];
                    float q = lsq[0][lr] + lsq[1][lr];
                    float mu = s * (1.f / 128.f);
                    float var = q * (1.f / 128.f) - mu * mu;
                    float rs = rsqrtf(var + 1e-5f);
                    size_t rowoff = (size_t)gr * 128;
#pragma unroll
                    for (int n = 0; n < 4; n++) {
                        float y = fmaf((acc[m][n][j] - mu) * rs, gv[n], bv[n]);
                        int gc = cbase + n * 16;
                        if (outf) outf[rowoff + gc] = y;
                        if (outb) outb[rowoff + gc] = f2bf(y);
                    }
                }
            }
        }
    }
}

// ---------------- GAT aggregation (CSR) ----------------
__global__ __launch_bounds__(256) void k_gat(const u16* __restrict__ xlr,
                                             const u32* __restrict__ csr,
                                             const int* __restrict__ offs,
                                             const int* __restrict__ cnt,
                                             const float* __restrict__ att,
                                             const float* __restrict__ gbias,
                                             u16* __restrict__ x1b)
{
    const int node = blockIdx.x * 4 + (threadIdx.x >> 6);
    const int lane = threadIdx.x & 63;
    const int c0 = ((lane >> 3) << 4) + ((lane & 7) << 1);
    const float L2E = 1.44269504f;

    const float a0 = att[c0], a1 = att[c0 + 1];
    const u32 xrp = *(const u32*)(xlr + (size_t)node * 256 + 128 + c0);
    const float xr0 = bf2f((u16)xrp), xr1 = bf2f((u16)(xrp >> 16));
    const int beg = offs[node];
    const int end = beg + cnt[node];

    float m = -3.4e38f, s = 0.f, acc0 = 0.f, acc1 = 0.f;

    u32 xg[4];
    auto loadgrp = [&](int ee) {
#pragma unroll
        for (int i = 0; i < 4; i++) {
            int t = ee + i; t = t < end - 1 ? t : end - 1;
            int idx = (int)csr[t];
            xg[i] = *(const u32*)(xlr + (size_t)idx * 256 + c0);
        }
    };
    if (beg < end) loadgrp(beg);

    for (int e = beg; e < end; e += 4) {
        u32 cur0 = xg[0], cur1 = xg[1], cur2 = xg[2], cur3 = xg[3];
        if (e + 4 < end) loadgrp(e + 4);

        float xl0[4], xl1[4], p[4];
        u32 curs[4] = {cur0, cur1, cur2, cur3};
#pragma unroll
        for (int i = 0; i < 4; i++) {
            xl0[i] = bf2f((u16)curs[i]);
            xl1[i] = bf2f((u16)(curs[i] >> 16));
            float t0 = xl0[i] + xr0; t0 = (t0 > 0.f) ? t0 : 0.2f * t0;
            float t1 = xl1[i] + xr1; t1 = (t1 > 0.f) ? t1 : 0.2f * t1;
            float pp = fmaf(t0, a0, t1 * a1);
            pp += __shfl_xor(pp, 1, 8);
            pp += __shfl_xor(pp, 2, 8);
            pp += __shfl_xor(pp, 4, 8);
            p[i] = (e + i < end) ? pp * L2E : -INFINITY;
        }
        float mnew = fmaxf(m, fmaxf(fmaxf(p[0], p[1]), fmaxf(p[2], p[3])));
        float sc = exp2f(m - mnew);
        float w0 = exp2f(p[0] - mnew), w1 = exp2f(p[1] - mnew);
        float w2 = exp2f(p[2] - mnew), w3 = exp2f(p[3] - mnew);
        s = fmaf(s, sc, (w0 + w1) + (w2 + w3));
        acc0 = fmaf(acc0, sc, fmaf(w0, xl0[0], fmaf(w1, xl0[1], fmaf(w2, xl0[2], w3 * xl0[3]))));
        acc1 = fmaf(acc1, sc, fmaf(w0, xl1[0], fmaf(w1, xl1[1], fmaf(w2, xl1[2], w3 * xl1[3]))));
        m = mnew;
    }

    float inv = 1.f / (s + 1e-16f);
    float o0 = acc0 * inv + gbias[c0];
    float o1 = acc1 * inv + gbias[c0 + 1];
    u32 pk = (u32)f2bf(o0) | ((u32)f2bf(o1) << 16);
    *(u32*)(x1b + (size_t)node * CC + c0) = pk;
}

extern "C" void kernel_launch(void* const* d_in, const int* in_sizes, int n_in,
                              void* d_out, int out_size, void* d_ws, size_t ws_size,
                              hipStream_t stream) {
    const float* x0    = (const float*)d_in[0];
    const int*   edges = (const int*)d_in[1];      // [2,E]: src row, dst row
    const float* lin_l = (const float*)d_in[2];
    const float* lin_r = (const float*)d_in[3];
    const float* att   = (const float*)d_in[4];
    const float* gbias = (const float*)d_in[5];
    const float* Ww    = (const float*)d_in[6];
    const float* g1    = (const float*)d_in[7];
    const float* b1    = (const float*)d_in[8];
    const float* w1    = (const float*)d_in[9];
    const float* mb1   = (const float*)d_in[10];
    const float* w2    = (const float*)d_in[11];
    const float* mb2   = (const float*)d_in[12];
    const float* g2    = (const float*)d_in[13];
    const float* b2    = (const float*)d_in[14];
    float* out = (float*)d_out;

    char* ws = (char*)d_ws;
    size_t off = 0;
    auto alloc = [&](size_t bytes) {
        char* p = ws + off;
        off += (bytes + 255) & ~(size_t)255;
        return p;
    };
    u16*   x0b   = (u16*)alloc((size_t)NN * CC * 2);      // reused as x3b
    u16*   xlr   = (u16*)alloc((size_t)NN * 256 * 2);     // reused as hb
    u16*   x1b   = (u16*)alloc((size_t)NN * CC * 2);
    u16*   Wa    = (u16*)alloc(256 * 128 * 2);            // [lin_l ; lin_r]
    u16*   Wb    = (u16*)alloc(128 * 128 * 2);
    u16*   W1    = (u16*)alloc(256 * 128 * 2);
    u16*   W2    = (u16*)alloc(128 * 256 * 2);
    int*   bucketCnt   = (int*)alloc((size_t)NB * BSTRIDE * 4);
    u32*   bucketEdges = (u32*)alloc((size_t)NB * BCAP * 4);
    int*   offsA       = (int*)alloc((size_t)NN * 4);
    int*   cntA        = (int*)alloc((size_t)NN * 4);
    u16*   x3b = x0b;
    u16*   hb  = xlr;
    (void)in_sizes; (void)n_in; (void)out_size; (void)ws_size;

    // 1) init: conversions + zero bucket counters
    k_init<<<2161, 256, 0, stream>>>(x0, x0b, lin_l, lin_r, Ww, w1, w2,
                                     Wa, Wa + 16384, Wb, W1, W2, bucketCnt);

    // 2) edge bucketing (pass 1) + per-bucket CSR (pass 2)
    k_p1<<<1024, 256, 0, stream>>>(edges, edges + EE, bucketCnt, bucketEdges);
    k_p2<<<NB, 256, 0, stream>>>(bucketCnt, bucketEdges, offsA, cntA);

    // 3) stage-1 GEMM: [x_l | x_r] = x0 @ [lin_l;lin_r]^T  -> xlr bf16 [N,256]
    k_gemm<128, false, false, false, false><<<dim3(782, 2), 256, 0, stream>>>(
        x0b, Wa, nullptr, nullptr, nullptr, nullptr, nullptr, xlr, NN, 256);

    // 4) GAT aggregation -> x1 bf16
    k_gat<<<NN / 4, 256, 0, stream>>>(xlr, bucketEdges, offsA, cntA, att, gbias, x1b);

    // 5+6) x3 = LN(x1 @ W^T + x0)  fused -> x3b bf16
    k_gemm<128, false, false, true, true><<<dim3(782, 1), 256, 0, stream>>>(
        x1b, Wb, nullptr, x0b, g1, b1, nullptr, x3b, NN, 128);

    // 7) h = relu(x3 @ mlp_w1^T + b1)  -> bf16 [N,256]
    k_gemm<128, true, true, false, false><<<dim3(782, 2), 256, 0, stream>>>(
        x3b, W1, mb1, nullptr, nullptr, nullptr, nullptr, hb, NN, 256);

    // 8+9) out = LN(h @ mlp_w2^T + b2 + x3)  fused -> f32 out
    k_gemm<256, true, false, true, true><<<dim3(782, 1), 256, 0, stream>>>(
        hb, W2, mb2, x3b, g2, b2, out, nullptr, NN, 128);
}

// Round 6
// 308.778 us; speedup vs baseline: 2.0115x; 1.1024x over previous
//
#include <hip/hip_runtime.h>

#define NN 100000
#define CC 128
#define HHEADS 8
#define EE 1600000
#define NB 196          // buckets of 512 nodes
#define BCAP 10240      // bucket capacity (mean 8192, +22 sigma)
#define BSTRIDE 16      // bucketCnt padded to one per 64B line

typedef unsigned short u16;
typedef unsigned int u32;
typedef __attribute__((ext_vector_type(8))) u16 u16x8;
typedef __attribute__((ext_vector_type(4))) u16 u16x4;
typedef __attribute__((ext_vector_type(8))) __bf16 bf16x8;
typedef __attribute__((ext_vector_type(4))) float f32x4;
typedef __attribute__((ext_vector_type(2))) float f32x2;

__device__ __forceinline__ float bf2f(u16 u) {
    union { u32 i; float f; } v; v.i = ((u32)u) << 16; return v.f;
}
__device__ __forceinline__ u16 f2bf(float f) {
    union { float f; u32 i; } v; v.f = f;
    u32 r = v.i + 0x7FFFu + ((v.i >> 16) & 1u);
    return (u16)(r >> 16);
}
__device__ __forceinline__ float fexp2(float x) {
    float r;
    asm volatile("v_exp_f32 %0, %1" : "=v"(r) : "v"(x));
    return r;
}

__device__ __forceinline__ f32x4 mfma16(u16x8 a, u16x8 b, f32x4 c) {
    return __builtin_amdgcn_mfma_f32_16x16x32_bf16(
        __builtin_bit_cast(bf16x8, a), __builtin_bit_cast(bf16x8, b), c, 0, 0, 0);
}

// ---------------- init: x0 cvt + weight cvts + zero bucket counters ----------------
__global__ __launch_bounds__(256) void k_init(
    const float* __restrict__ x0, u16* __restrict__ x0b,
    const float* __restrict__ s0, const float* __restrict__ s1,
    const float* __restrict__ s2, const float* __restrict__ s3,
    const float* __restrict__ s4,
    u16* __restrict__ d0, u16* __restrict__ d1, u16* __restrict__ d2,
    u16* __restrict__ d3, u16* __restrict__ d4,
    int* __restrict__ bucketCnt)
{
    int b = blockIdx.x, tid = threadIdx.x;
    if (b < 2048) {
        const int n = NN * CC;
        const int stride = 2048 * 256 * 4;
        for (int i = (b * 256 + tid) * 4; i < n; i += stride) {
            float4 v = *(const float4*)(x0 + i);
            u16x4 o;
            o.x = f2bf(v.x); o.y = f2bf(v.y); o.z = f2bf(v.z); o.w = f2bf(v.w);
            *(u16x4*)(x0b + i) = o;
        }
    } else if (b < 2160) {
        int wb = b - 2048;
        const float* s; u16* d; int boff;
        if (wb < 16)      { s = s0; d = d0; boff = wb; }
        else if (wb < 32) { s = s1; d = d1; boff = wb - 16; }
        else if (wb < 48) { s = s2; d = d2; boff = wb - 32; }
        else if (wb < 80) { s = s3; d = d3; boff = wb - 48; }
        else              { s = s4; d = d4; boff = wb - 80; }
        int i = boff * 1024 + tid * 4;
        float4 v = *(const float4*)(s + i);
        u16x4 o;
        o.x = f2bf(v.x); o.y = f2bf(v.y); o.z = f2bf(v.z); o.w = f2bf(v.w);
        *(u16x4*)(d + i) = o;
    } else {
        for (int i = tid; i < NB * BSTRIDE; i += 256) bucketCnt[i] = 0;
    }
}

// ---------------- pass 1: bucket edges by dst>>9 ----------------
__global__ __launch_bounds__(256) void k_p1(const int* __restrict__ src,
                                            const int* __restrict__ dst,
                                            int* __restrict__ bucketCnt,
                                            u32* __restrict__ bucketEdges)
{
    __shared__ u32 hist[NB], base[NB], hist2[NB];
    const int b = blockIdx.x, tid = threadIdx.x;
    const int beg = b * 1563;
    const int end = (beg + 1563 < EE) ? beg + 1563 : EE;
    for (int t = tid; t < NB; t += 256) { hist[t] = 0; hist2[t] = 0; }
    __syncthreads();

    int es[7], ds[7];
#pragma unroll
    for (int j = 0; j < 7; j++) {
        int i = beg + tid + j * 256;
        if (i < end) { es[j] = src[i]; ds[j] = dst[i]; }
        else { es[j] = -1; ds[j] = 0; }
    }
#pragma unroll
    for (int j = 0; j < 7; j++)
        if (es[j] >= 0) atomicAdd(&hist[(u32)ds[j] >> 9], 1u);
    __syncthreads();
    for (int t = tid; t < NB; t += 256)
        base[t] = (u32)atomicAdd(&bucketCnt[t * BSTRIDE], (int)hist[t]);
    __syncthreads();
#pragma unroll
    for (int j = 0; j < 7; j++) {
        if (es[j] >= 0) {
            u32 bb = (u32)ds[j] >> 9;
            u32 r = atomicAdd(&hist2[bb], 1u);
            u32 pos = base[bb] + r;
            if (pos < BCAP)
                bucketEdges[(size_t)bb * BCAP + pos] = (u32)es[j] | ((u32)(ds[j] & 511) << 17);
        }
    }
}

// ---------------- pass 2: per-bucket CSR build ----------------
__global__ __launch_bounds__(256) void k_p2(const int* __restrict__ bucketCnt,
                                            u32* __restrict__ bucketEdges,
                                            int* __restrict__ offs,
                                            int* __restrict__ cnt)
{
    __shared__ u32 ebuf[BCAP];                 // 40 KB
    __shared__ u32 ncnt[512], loff[512], ssum[256];
    const int b = blockIdx.x, tid = threadIdx.x;
    int n = bucketCnt[b * BSTRIDE]; n = n < BCAP ? n : BCAP;
    u32* be = bucketEdges + (size_t)b * BCAP;

    for (int i = tid; i < n; i += 256) ebuf[i] = be[i];
    ncnt[tid] = 0; ncnt[tid + 256] = 0;
    __syncthreads();
    for (int i = tid; i < n; i += 256) atomicAdd(&ncnt[(ebuf[i] >> 17) & 511], 1u);
    __syncthreads();

    u32 a0 = ncnt[2 * tid], a1 = ncnt[2 * tid + 1];
    ssum[tid] = a0 + a1;
    __syncthreads();
    for (int o = 1; o < 256; o <<= 1) {
        u32 v = ssum[tid];
        u32 add = (tid >= o) ? ssum[tid - o] : 0;
        __syncthreads();
        ssum[tid] = v + add;
        __syncthreads();
    }
    u32 excl = ssum[tid] - (a0 + a1);
    loff[2 * tid] = excl;
    loff[2 * tid + 1] = excl + a0;

    int node0 = b * 512 + 2 * tid;
    if (node0 < NN)     { offs[node0]     = b * BCAP + (int)excl;            cnt[node0]     = (int)a0; }
    if (node0 + 1 < NN) { offs[node0 + 1] = b * BCAP + (int)(excl + a0);     cnt[node0 + 1] = (int)a1; }

    ncnt[tid] = 0; ncnt[tid + 256] = 0;
    __syncthreads();
    for (int i = tid; i < n; i += 256) {
        u32 e = ebuf[i];
        u32 ln = (e >> 17) & 511;
        u32 r = atomicAdd(&ncnt[ln], 1u);
        be[loff[ln] + r] = e & 0x1FFFFu;
    }
}

// ---------------- bf16 MFMA GEMM, BK=128, optional fused slim LayerNorm ----------------
template<int K, bool BIAS, bool RELU, bool RESIDB, bool LNF>
__global__ __launch_bounds__(256, 2) void k_gemm(
    const u16* __restrict__ A, const u16* __restrict__ B,
    const float* __restrict__ bias, const u16* __restrict__ residb,
    const float* __restrict__ g, const float* __restrict__ bln,
    float* __restrict__ outf, u16* __restrict__ outb, int M, int NC)
{
    __shared__ __align__(16) u16 As[128 * 128];   // 32 KB
    __shared__ __align__(16) u16 Bs[128 * 128];   // 32 KB
    __shared__ float lsum[2][128], lsq[2][128];   // 2 KB

    const int tid = threadIdx.x;
    const int lane = tid & 63;
    const int w = tid >> 6;
    const int wr = w >> 1, wc = w & 1;
    const int row0 = blockIdx.x * 128;
    const int col0 = blockIdx.y * 128;
    f32x4 acc[4][4] = {};

    for (int kt = 0; kt < K; kt += 128) {
#pragma unroll
        for (int i = 0; i < 8; i++) {
            int c = i * 256 + tid;
            int r = c >> 4;
            int kc = (c & 15) * 8;
            int ar = row0 + r; ar = ar < M ? ar : M - 1;
            __builtin_amdgcn_global_load_lds(
                (const __attribute__((address_space(1))) u32*)(A + (size_t)ar * K + kt + kc),
                (__attribute__((address_space(3))) u32*)(As + r * 128 + kc), 16, 0, 0);
            __builtin_amdgcn_global_load_lds(
                (const __attribute__((address_space(1))) u32*)(B + (size_t)(col0 + r) * K + kt + kc),
                (__attribute__((address_space(3))) u32*)(Bs + r * 128 + kc), 16, 0, 0);
        }
        asm volatile("s_waitcnt vmcnt(0)" ::: "memory");
        __syncthreads();
#pragma unroll
        for (int kk = 0; kk < 4; kk++) {
            const int ko = kk * 32 + (lane >> 4) * 8;
            u16x8 af[4], bfr[4];
#pragma unroll
            for (int m = 0; m < 4; m++)
                af[m] = *(const u16x8*)(As + (wr * 64 + m * 16 + (lane & 15)) * 128 + ko);
#pragma unroll
            for (int n = 0; n < 4; n++)
                bfr[n] = *(const u16x8*)(Bs + (wc * 64 + n * 16 + (lane & 15)) * 128 + ko);
#pragma unroll
            for (int m = 0; m < 4; m++)
#pragma unroll
                for (int n = 0; n < 4; n++)
                    acc[m][n] = mfma16(af[m], bfr[n], acc[m][n]);
        }
        __syncthreads();
    }

    const int rbase = wr * 64 + ((lane >> 4) << 2);
    const int cbase = wc * 64 + (lane & 15);

    if constexpr (!LNF) {
#pragma unroll
        for (int m = 0; m < 4; m++) {
#pragma unroll
            for (int j = 0; j < 4; j++) {
                int gr = row0 + rbase + m * 16 + j;
                if (gr < M) {
                    size_t rowoff = (size_t)gr * NC;
#pragma unroll
                    for (int n = 0; n < 4; n++) {
                        int gc = col0 + cbase + n * 16;
                        float v = acc[m][n][j];
                        if constexpr (BIAS)  v += bias[gc];
                        if constexpr (RELU)  v = fmaxf(v, 0.f);
                        if (outf) outf[rowoff + gc] = v;
                        if (outb) outb[rowoff + gc] = f2bf(v);
                    }
                }
            }
        }
    } else {
        float gv[4], bv[4];
#pragma unroll
        for (int n = 0; n < 4; n++) { gv[n] = g[cbase + n * 16]; bv[n] = bln[cbase + n * 16]; }
#pragma unroll
        for (int m = 0; m < 4; m++) {
#pragma unroll
            for (int j = 0; j < 4; j++) {
                int lr = rbase + m * 16 + j;
                int gr = row0 + lr; gr = gr < M ? gr : M - 1;
                float s = 0.f, q = 0.f;
#pragma unroll
                for (int n = 0; n < 4; n++) {
                    float v = acc[m][n][j];
                    if constexpr (BIAS)   v += bias[cbase + n * 16];
                    if constexpr (RESIDB) v += bf2f(residb[(size_t)gr * 128 + cbase + n * 16]);
                    if constexpr (RELU)   v = fmaxf(v, 0.f);
                    acc[m][n][j] = v;
                    s += v; q += v * v;
                }
                s += __shfl_xor(s, 1, 16); q += __shfl_xor(q, 1, 16);
                s += __shfl_xor(s, 2, 16); q += __shfl_xor(q, 2, 16);
                s += __shfl_xor(s, 4, 16); q += __shfl_xor(q, 4, 16);
                s += __shfl_xor(s, 8, 16); q += __shfl_xor(q, 8, 16);
                if ((lane & 15) == 0) { lsum[wc][lr] = s; lsq[wc][lr] = q; }
            }
        }
        __syncthreads();
#pragma unroll
        for (int m = 0; m < 4; m++) {
#pragma unroll
            for (int j = 0; j < 4; j++) {
                int lr = rbase + m * 16 + j;
                int gr = row0 + lr;
                if (gr < M) {
                    float s = lsum[0][lr] + lsum[1][lr];
                    float q = lsq[0][lr] + lsq[1][lr];
                    float mu = s * (1.f / 128.f);
                    float var = q * (1.f / 128.f) - mu * mu;
                    float rs = rsqrtf(var + 1e-5f);
                    size_t rowoff = (size_t)gr * 128;
#pragma unroll
                    for (int n = 0; n < 4; n++) {
                        float y = fmaf((acc[m][n][j] - mu) * rs, gv[n], bv[n]);
                        int gc = cbase + n * 16;
                        if (outf) outf[rowoff + gc] = y;
                        if (outb) outb[rowoff + gc] = f2bf(y);
                    }
                }
            }
        }
    }
}

// ---------------- GAT aggregation: lane = slot(2b) x sub(4b), 8 ch/lane ----------------
// 4 concurrent edge streams per wave; per-lane online softmax; in-lane dot + 1 shfl.
__global__ __launch_bounds__(256) void k_gat(const u16* __restrict__ xlr,
                                             const u32* __restrict__ csr,
                                             const int* __restrict__ offs,
                                             const int* __restrict__ cnt,
                                             const float* __restrict__ att,
                                             const float* __restrict__ gbias,
                                             u16* __restrict__ x1b)
{
    const int node = blockIdx.x * 4 + (threadIdx.x >> 6);
    const int lane = threadIdx.x & 63;
    const int slot = lane >> 4;          // 0..3 edge stream
    const int sub  = lane & 15;          // 8-channel chunk
    const int c0   = sub * 8;
    const float L2E = 1.44269504f;

    // att coefficients pre-scaled by log2(e)
    f32x4 alo = *(const f32x4*)(att + c0);
    f32x4 ahi = *(const f32x4*)(att + c0 + 4);
    f32x2 av[4];
    av[0] = f32x2{alo[0], alo[1]} * L2E; av[1] = f32x2{alo[2], alo[3]} * L2E;
    av[2] = f32x2{ahi[0], ahi[1]} * L2E; av[3] = f32x2{ahi[2], ahi[3]} * L2E;

    u16x8 xr8 = *(const u16x8*)(xlr + (size_t)node * 256 + 128 + c0);
    f32x2 xrv[4];
#pragma unroll
    for (int j = 0; j < 4; j++) xrv[j] = f32x2{bf2f(xr8[2 * j]), bf2f(xr8[2 * j + 1])};

    const int beg = offs[node];
    const int deg = cnt[node];
    const int ng = (deg + 3) >> 2;

    float m = -3.4e38f, s = 0.f;
    f32x2 accv[4] = {};

    u16x8 xgA = {}, xgB = {};
    int ixC = 0;
    if (deg > 0) {
        int dm1 = deg - 1;
        int e0 = slot      < dm1 ? slot      : dm1;
        int e1 = slot + 4  < dm1 ? slot + 4  : dm1;
        int e2 = slot + 8  < dm1 ? slot + 8  : dm1;
        int i0 = (int)csr[beg + e0];
        int i1 = (int)csr[beg + e1];
        ixC    = (int)csr[beg + e2];
        xgA = *(const u16x8*)(xlr + (size_t)i0 * 256 + c0);
        xgB = *(const u16x8*)(xlr + (size_t)i1 * 256 + c0);
    }

    for (int g = 0; g < ng; g++) {
        u16x8 cur = xgA;
        xgA = xgB;
        // prefetch: gather for group g+2 (idx already in flight), idx for g+3
        xgB = *(const u16x8*)(xlr + (size_t)ixC * 256 + c0);
        int en = 4 * (g + 3) + slot; en = en < deg - 1 ? en : deg - 1;
        ixC = (int)csr[beg + (en > 0 ? en : 0)];

        const int e = 4 * g + slot;
        f32x2 xlv[4];
        f32x2 dot = {0.f, 0.f};
#pragma unroll
        for (int j = 0; j < 4; j++) {
            f32x2 xl = f32x2{bf2f(cur[2 * j]), bf2f(cur[2 * j + 1])};
            xlv[j] = xl;
            f32x2 t = xl + xrv[j];
            f32x2 t2 = t * 0.2f;
            f32x2 lr = f32x2{fmaxf(t.x, t2.x), fmaxf(t.y, t2.y)};
            dot += av[j] * lr;
        }
        float p = dot.x + dot.y;
        p += __shfl_xor(p, 1);                      // combine half-head partner
        p = (e < deg) ? p : -INFINITY;
        float mnew = fmaxf(m, p);
        float sc = fexp2(m - mnew);
        float wgt = fexp2(p - mnew);
        s = s * sc + wgt;
#pragma unroll
        for (int j = 0; j < 4; j++) accv[j] = accv[j] * sc + xlv[j] * wgt;
        m = mnew;
    }

    // cross-slot merge (butterfly over lane bits 4,5)
    float mg = m;
    mg = fmaxf(mg, __shfl_xor(mg, 16));
    mg = fmaxf(mg, __shfl_xor(mg, 32));
    float sc = fexp2(m - mg);
    s *= sc;
    s += __shfl_xor(s, 16);
    s += __shfl_xor(s, 32);
#pragma unroll
    for (int j = 0; j < 4; j++) {
        accv[j] *= sc;
        accv[j].x += __shfl_xor(accv[j].x, 16);
        accv[j].y += __shfl_xor(accv[j].y, 16);
        accv[j].x += __shfl_xor(accv[j].x, 32);
        accv[j].y += __shfl_xor(accv[j].y, 32);
    }

    if (slot == 0) {
        float inv = 1.f / (s + 1e-16f);
        u16x8 o;
#pragma unroll
        for (int j = 0; j < 4; j++) {
            o[2 * j]     = f2bf(fmaf(accv[j].x, inv, gbias[c0 + 2 * j]));
            o[2 * j + 1] = f2bf(fmaf(accv[j].y, inv, gbias[c0 + 2 * j + 1]));
        }
        *(u16x8*)(x1b + (size_t)node * CC + c0) = o;
    }
}

extern "C" void kernel_launch(void* const* d_in, const int* in_sizes, int n_in,
                              void* d_out, int out_size, void* d_ws, size_t ws_size,
                              hipStream_t stream) {
    const float* x0    = (const float*)d_in[0];
    const int*   edges = (const int*)d_in[1];      // [2,E]: src row, dst row
    const float* lin_l = (const float*)d_in[2];
    const float* lin_r = (const float*)d_in[3];
    const float* att   = (const float*)d_in[4];
    const float* gbias = (const float*)d_in[5];
    const float* Ww    = (const float*)d_in[6];
    const float* g1    = (const float*)d_in[7];
    const float* b1    = (const float*)d_in[8];
    const float* w1    = (const float*)d_in[9];
    const float* mb1   = (const float*)d_in[10];
    const float* w2    = (const float*)d_in[11];
    const float* mb2   = (const float*)d_in[12];
    const float* g2    = (const float*)d_in[13];
    const float* b2    = (const float*)d_in[14];
    float* out = (float*)d_out;

    char* ws = (char*)d_ws;
    size_t off = 0;
    auto alloc = [&](size_t bytes) {
        char* p = ws + off;
        off += (bytes + 255) & ~(size_t)255;
        return p;
    };
    u16*   x0b   = (u16*)alloc((size_t)NN * CC * 2);      // reused as x3b
    u16*   xlr   = (u16*)alloc((size_t)NN * 256 * 2);     // reused as hb
    u16*   x1b   = (u16*)alloc((size_t)NN * CC * 2);
    u16*   Wa    = (u16*)alloc(256 * 128 * 2);            // [lin_l ; lin_r]
    u16*   Wb    = (u16*)alloc(128 * 128 * 2);
    u16*   W1    = (u16*)alloc(256 * 128 * 2);
    u16*   W2    = (u16*)alloc(128 * 256 * 2);
    int*   bucketCnt   = (int*)alloc((size_t)NB * BSTRIDE * 4);
    u32*   bucketEdges = (u32*)alloc((size_t)NB * BCAP * 4);
    int*   offsA       = (int*)alloc((size_t)NN * 4);
    int*   cntA        = (int*)alloc((size_t)NN * 4);
    u16*   x3b = x0b;
    u16*   hb  = xlr;
    (void)in_sizes; (void)n_in; (void)out_size; (void)ws_size;

    // 1) init: conversions + zero bucket counters
    k_init<<<2161, 256, 0, stream>>>(x0, x0b, lin_l, lin_r, Ww, w1, w2,
                                     Wa, Wa + 16384, Wb, W1, W2, bucketCnt);

    // 2) edge bucketing (pass 1) + per-bucket CSR (pass 2)
    k_p1<<<1024, 256, 0, stream>>>(edges, edges + EE, bucketCnt, bucketEdges);
    k_p2<<<NB, 256, 0, stream>>>(bucketCnt, bucketEdges, offsA, cntA);

    // 3) stage-1 GEMM: [x_l | x_r] = x0 @ [lin_l;lin_r]^T  -> xlr bf16 [N,256]
    k_gemm<128, false, false, false, false><<<dim3(782, 2), 256, 0, stream>>>(
        x0b, Wa, nullptr, nullptr, nullptr, nullptr, nullptr, xlr, NN, 256);

    // 4) GAT aggregation -> x1 bf16
    k_gat<<<NN / 4, 256, 0, stream>>>(xlr, bucketEdges, offsA, cntA, att, gbias, x1b);

    // 5+6) x3 = LN(x1 @ W^T + x0)  fused -> x3b bf16
    k_gemm<128, false, false, true, true><<<dim3(782, 1), 256, 0, stream>>>(
        x1b, Wb, nullptr, x0b, g1, b1, nullptr, x3b, NN, 128);

    // 7) h = relu(x3 @ mlp_w1^T + b1)  -> bf16 [N,256]
    k_gemm<128, true, true, false, false><<<dim3(782, 2), 256, 0, stream>>>(
        x3b, W1, mb1, nullptr, nullptr, nullptr, nullptr, hb, NN, 256);

    // 8+9) out = LN(h @ mlp_w2^T + b2 + x3)  fused -> f32 out
    k_gemm<256, true, false, true, true><<<dim3(782, 1), 256, 0, stream>>>(
        hb, W2, mb2, x3b, g2, b2, out, nullptr, NN, 128);
}